// Round 6
// baseline (260.345 us; speedup 1.0000x reference)
//
#include <hip/hip_runtime.h>
#include <stdint.h>

#define NROWS 4096
#define DIM   128
#define KB    8
#define NS    7            // K-1 negatives per anchor
#define TCH   16           // candidate chunks (256 cands each)
#define NPAIR 2048
#define HALF_CNT 58720256u // (4096*7*4096)/2

typedef __bf16 v8bf __attribute__((ext_vector_type(8)));
typedef float  v4f  __attribute__((ext_vector_type(4)));

__device__ __forceinline__ uint32_t rotl32(uint32_t x, int r) {
    return (x << r) | (x >> (32 - r));
}

// JAX threefry2x32, key = [0, 42], 20 rounds. (c0,c1)=(L, L+HALF_CNT):
// o0 = bits for flat index L, o1 = bits for flat index L+HALF_CNT.
__device__ __forceinline__ void threefry2x32(uint32_t c0, uint32_t c1,
                                             uint32_t& o0, uint32_t& o1) {
    const uint32_t ks0 = 0u;
    const uint32_t ks1 = 42u;
    const uint32_t ks2 = 0x1BD11BDAu ^ ks0 ^ ks1;
    uint32_t x0 = c0 + ks0;
    uint32_t x1 = c1 + ks1;
#define TF_R(r) { x0 += x1; x1 = rotl32(x1, r); x1 ^= x0; }
    TF_R(13) TF_R(15) TF_R(26) TF_R(6)
    x0 += ks1; x1 += ks2 + 1u;
    TF_R(17) TF_R(29) TF_R(16) TF_R(24)
    x0 += ks2; x1 += ks0 + 2u;
    TF_R(13) TF_R(15) TF_R(26) TF_R(6)
    x0 += ks0; x1 += ks1 + 3u;
    TF_R(17) TF_R(29) TF_R(16) TF_R(24)
    x0 += ks1; x1 += ks2 + 4u;
    TF_R(13) TF_R(15) TF_R(26) TF_R(6)
    x0 += ks2; x1 += ks0 + 5u;
#undef TF_R
    o0 = x0; o1 = x1;
}

// gumbel = -ln(-ln(u)), u = f + tiny, via native v_log_f32 (log2)
__device__ __forceinline__ float gumbel_of(uint32_t b) {
    float f = __uint_as_float((b >> 9) | 0x3f800000u) - 1.0f;   // [0,1)
    float u = f + 1.17549435e-38f;
    float l1 = __log2f(u);                    // <= 0
    float inner = -0.69314718055994531f * l1; // -ln(u) >= 0
    float l2 = __log2f(inner);
    return -0.69314718055994531f * l2;
}

// 7-wide interleaved threefry round / key-injection (explicit ILP-7)
__device__ __forceinline__ void tfr7(uint32_t x0[NS], uint32_t x1[NS], int r) {
#pragma unroll
    for (int j = 0; j < NS; ++j) {
        x0[j] += x1[j];
        x1[j] = rotl32(x1[j], r);
        x1[j] ^= x0[j];
    }
}
__device__ __forceinline__ void inj7(uint32_t x0[NS], uint32_t x1[NS],
                                     uint32_t a, uint32_t b) {
#pragma unroll
    for (int j = 0; j < NS; ++j) { x0[j] += a; x1[j] += b; }
}

// ---------------- kernel 1: normalize -> bf16 hi/lo planes + sq -----------
__global__ void knorm(const float* __restrict__ x, __bf16* __restrict__ xh,
                      __bf16* __restrict__ xl, float* __restrict__ sqv) {
    const int i = blockIdx.x;
    const int t = threadIdx.x;  // 64 threads, 2 elems each
    float2 v = ((const float2*)(x + (size_t)i * DIM))[t];
    float s = v.x * v.x + v.y * v.y;
#pragma unroll
    for (int m = 32; m > 0; m >>= 1) s += __shfl_xor(s, m, 64);
    float norm = sqrtf(s) + 1e-5f;
    float ox = v.x / norm, oy = v.y / norm;
    __bf16 hx = (__bf16)ox, hy = (__bf16)oy;
    float lx = ox - (float)hx, ly = oy - (float)hy;
    union { __bf16 b[2]; uint32_t u; } ph, pl;
    ph.b[0] = hx; ph.b[1] = hy;
    pl.b[0] = (__bf16)lx; pl.b[1] = (__bf16)ly;
    ((uint32_t*)xh)[i * 64 + t] = ph.u;
    ((uint32_t*)xl)[i * 64 + t] = pl.u;
    float s2 = ox * ox + oy * oy;
#pragma unroll
    for (int m = 32; m > 0; m >>= 1) s2 += __shfl_xor(s2, m, 64);
    if (t == 0) sqv[i] = s2;
}

// ---------------- kernel 2a: MFMA dists -> compacted candidate lists ------
// Atomic-return consumption deferred one cg iteration: the L2 round trip
// hides under the next iteration's MFMA+lg work instead of serializing.
__global__ __launch_bounds__(256, 3) void kdist(
        const __bf16* __restrict__ xh, const __bf16* __restrict__ xl,
        const float* __restrict__ sqv,
        int* __restrict__ cnt, unsigned short* __restrict__ t16,
        float2* __restrict__ lgp) {
    const int lane  = threadIdx.x & 63;
    const int chunk = (blockIdx.x << 2) + (threadIdx.x >> 6);   // 0..15
    const int grp   = blockIdx.y;   // 0..255
    const int rlo = lane & 15;
    const int khi = lane >> 4;
    const unsigned int below = (1u << rlo) - 1u;

    const int afr = grp * 8 + (rlo >> 1) + ((rlo & 1) << 11);
    v8bf ah[4], al[4];
#pragma unroll
    for (int ks = 0; ks < 4; ++ks) {
        const size_t off = (size_t)afr * DIM + ks * 32 + khi * 8;
        ah[ks] = *(const v8bf*)(xh + off);
        al[ks] = *(const v8bf*)(xl + off);
    }

    const int base = grp * 8 + khi * 2;   // pairA = base, pairB = base+1
    float sqA[4];
    sqA[0] = sqv[base];
    sqA[1] = sqv[base + 2048];
    sqA[2] = sqv[base + 1];
    sqA[3] = sqv[base + 2049];

    const int tcol0 = chunk * 256 + rlo;

    v8bf bhn[4], bln[4];
    float sqn;
    {
        const size_t boff = (size_t)tcol0 * DIM + khi * 8;
#pragma unroll
        for (int ks = 0; ks < 4; ++ks) {
            bhn[ks] = *(const v8bf*)(xh + boff + ks * 32);
            bln[ks] = *(const v8bf*)(xl + boff + ks * 32);
        }
        sqn = sqv[tcol0];
    }

    // pending-append state (flushed one iteration later)
    bool puA = false, puB = false;
    unsigned int psubA = 0, psubB = 0;
    int poldA = 0, poldB = 0;
    int ptcol = 0;
    float plgA0 = 0.f, plgA1 = 0.f, plgB0 = 0.f, plgB1 = 0.f;

#pragma unroll 1
    for (int cg = 0; cg < 16; ++cg) {
        v8bf bhc[4], blc[4];
#pragma unroll
        for (int ks = 0; ks < 4; ++ks) { bhc[ks] = bhn[ks]; blc[ks] = bln[ks]; }
        const float sqB = sqn;
        const int tcol = tcol0 + cg * 16;

        if (cg < 15) {
            const size_t boff = (size_t)(tcol + 16) * DIM + khi * 8;
#pragma unroll
            for (int ks = 0; ks < 4; ++ks) {
                bhn[ks] = *(const v8bf*)(xh + boff + ks * 32);
                bln[ks] = *(const v8bf*)(xl + boff + ks * 32);
            }
            sqn = sqv[tcol + 16];
        }

        v4f acc1 = {0.f, 0.f, 0.f, 0.f};
        v4f acc2 = {0.f, 0.f, 0.f, 0.f};
        v4f acc3 = {0.f, 0.f, 0.f, 0.f};
#pragma unroll
        for (int ks = 0; ks < 4; ++ks) {
            acc1 = __builtin_amdgcn_mfma_f32_16x16x32_bf16(ah[ks], bhc[ks], acc1, 0, 0, 0);
            acc2 = __builtin_amdgcn_mfma_f32_16x16x32_bf16(ah[ks], blc[ks], acc2, 0, 0, 0);
            acc3 = __builtin_amdgcn_mfma_f32_16x16x32_bf16(al[ks], bhc[ks], acc3, 0, 0, 0);
        }

        const int tBlk = tcol >> 3;
        const bool bd0 = (tBlk != grp);
        const bool bd1 = (tBlk != grp + 256);

        float lg[4];
        bool  ic[4];
#pragma unroll
        for (int q = 0; q < 4; ++q) {
            float dot = acc1[q] + acc2[q] + acc3[q];
            float d2  = fmaf(-2.0f, dot, sqA[q] + sqB);
            float l1  = __log2f(d2);
            float t2  = fmaf(-0.25f, d2, 1.0f);
            float l2  = __log2f(t2);
            float lw  = fmaf(-43.66827237527655f, l1, -43.32169878499658f * l2);
            bool incl = (d2 < 1.96f) && ((q & 1) ? bd1 : bd0);
            ic[q] = incl;
            lg[q] = incl ? lw : -INFINITY;
        }

        const bool uA = ic[0] | ic[1];
        const bool uB = ic[2] | ic[3];
        unsigned long long ballA = __ballot(uA);
        unsigned long long ballB = __ballot(uB);
        unsigned int subA = (unsigned int)((ballA >> (khi * 16)) & 0xFFFFull);
        unsigned int subB = (unsigned int)((ballB >> (khi * 16)) & 0xFFFFull);
        int oldA = 0, oldB = 0;
        if (rlo == 0) {
            oldA = atomicAdd(&cnt[base], __popc(subA));
            oldB = atomicAdd(&cnt[base + 1], __popc(subB));
        }

        // flush PREVIOUS pending (its atomic return is long since back)
        {
            int bA = __shfl(poldA, khi * 16, 64);
            int bB = __shfl(poldB, khi * 16, 64);
            if (puA) {
                int slot = bA + __popc(psubA & below);
                t16[(size_t)base * 4096 + slot] = (unsigned short)ptcol;
                lgp[(size_t)base * 4096 + slot] = make_float2(plgA0, plgA1);
            }
            if (puB) {
                int slot = bB + __popc(psubB & below);
                t16[(size_t)(base + 1) * 4096 + slot] = (unsigned short)ptcol;
                lgp[(size_t)(base + 1) * 4096 + slot] = make_float2(plgB0, plgB1);
            }
        }

        // stash current
        puA = uA; puB = uB;
        psubA = subA; psubB = subB;
        poldA = oldA; poldB = oldB;
        ptcol = tcol;
        plgA0 = lg[0]; plgA1 = lg[1]; plgB0 = lg[2]; plgB1 = lg[3];
    }

    // final flush
    {
        int bA = __shfl(poldA, khi * 16, 64);
        int bB = __shfl(poldB, khi * 16, 64);
        if (puA) {
            int slot = bA + __popc(psubA & below);
            t16[(size_t)base * 4096 + slot] = (unsigned short)ptcol;
            lgp[(size_t)base * 4096 + slot] = make_float2(plgA0, plgA1);
        }
        if (puB) {
            int slot = bB + __popc(psubB & below);
            t16[(size_t)(base + 1) * 4096 + slot] = (unsigned short)ptcol;
            lgp[(size_t)(base + 1) * 4096 + slot] = make_float2(plgB0, plgB1);
        }
    }
}

// ---------------- kernel 2b: gumbel argmax over compacted lists -----------
// One 128-thread block per pair. Explicit 7-wide interleaved threefry keeps
// ILP=7 in the instruction stream. Tie-break total order (v greater)||(v
// equal && t smaller) makes the result independent of list order.
__global__ __launch_bounds__(128, 4) void kgum(
        const int* __restrict__ cnt, const unsigned short* __restrict__ t16,
        const float2* __restrict__ lgp, int* __restrict__ nidx) {
    const int p    = blockIdx.x;
    const int tid  = threadIdx.x;
    const int lane = tid & 63;
    const int wid  = tid >> 6;
    const int n    = cnt[p];
    const size_t bp = (size_t)p * 4096;
    const uint32_t pb = ((uint32_t)p * 7u) << 12;

    float bv0[NS], bv1[NS];
    int   bt0[NS], bt1[NS];
#pragma unroll
    for (int j = 0; j < NS; ++j) {
        bv0[j] = -INFINITY; bv1[j] = -INFINITY;
        bt0[j] = 0x7FFFFFFF; bt1[j] = 0x7FFFFFFF;
    }

    int e = tid;
    uint32_t tcur = 0;
    float2 lgcur = make_float2(0.f, 0.f);
    if (e < n) { tcur = t16[bp + e]; lgcur = lgp[bp + e]; }

#pragma unroll 1
    while (e < n) {
        const int en = e + 128;
        uint32_t tnx = 0;
        float2 lgnx = make_float2(0.f, 0.f);
        if (en < n) { tnx = t16[bp + en]; lgnx = lgp[bp + en]; }

        uint32_t x0[NS], x1[NS];
#pragma unroll
        for (int j = 0; j < NS; ++j) {
            uint32_t L = pb + ((uint32_t)j << 12) + tcur;
            x0[j] = L;
            x1[j] = L + (HALF_CNT + 42u);
        }
        tfr7(x0, x1, 13); tfr7(x0, x1, 15); tfr7(x0, x1, 26); tfr7(x0, x1, 6);
        inj7(x0, x1, 42u, 0x1BD11BF0u + 1u);
        tfr7(x0, x1, 17); tfr7(x0, x1, 29); tfr7(x0, x1, 16); tfr7(x0, x1, 24);
        inj7(x0, x1, 0x1BD11BF0u, 2u);
        tfr7(x0, x1, 13); tfr7(x0, x1, 15); tfr7(x0, x1, 26); tfr7(x0, x1, 6);
        inj7(x0, x1, 0u, 45u);
        tfr7(x0, x1, 17); tfr7(x0, x1, 29); tfr7(x0, x1, 16); tfr7(x0, x1, 24);
        inj7(x0, x1, 42u, 0x1BD11BF0u + 4u);
        tfr7(x0, x1, 13); tfr7(x0, x1, 15); tfr7(x0, x1, 26); tfr7(x0, x1, 6);
        inj7(x0, x1, 0x1BD11BF0u, 5u);

        const int ti = (int)tcur;
#pragma unroll
        for (int j = 0; j < NS; ++j) {
            float v0 = lgcur.x + gumbel_of(x0[j]);
            float v1 = lgcur.y + gumbel_of(x1[j]);
            if (v0 > bv0[j] || (v0 == bv0[j] && ti < bt0[j])) { bv0[j] = v0; bt0[j] = ti; }
            if (v1 > bv1[j] || (v1 == bv1[j] && ti < bt1[j])) { bv1[j] = v1; bt1[j] = ti; }
        }
        tcur = tnx; lgcur = lgnx; e = en;
    }

    __shared__ float sV[2][2][NS];
    __shared__ int   sT[2][2][NS];
#pragma unroll
    for (int j = 0; j < NS; ++j) {
        float v = bv0[j]; int t = bt0[j];
#pragma unroll
        for (int m = 1; m < 64; m <<= 1) {
            float v2 = __shfl_xor(v, m, 64);
            int   t2 = __shfl_xor(t, m, 64);
            if (v2 > v || (v2 == v && t2 < t)) { v = v2; t = t2; }
        }
        if (lane == 0) { sV[wid][0][j] = v; sT[wid][0][j] = t; }
        v = bv1[j]; t = bt1[j];
#pragma unroll
        for (int m = 1; m < 64; m <<= 1) {
            float v2 = __shfl_xor(v, m, 64);
            int   t2 = __shfl_xor(t, m, 64);
            if (v2 > v || (v2 == v && t2 < t)) { v = v2; t = t2; }
        }
        if (lane == 0) { sV[wid][1][j] = v; sT[wid][1][j] = t; }
    }
    __syncthreads();
    if (tid < 2 * NS) {
        const int r = tid / NS, j = tid - r * NS;
        float v  = sV[0][r][j]; int t  = sT[0][r][j];
        float v2 = sV[1][r][j]; int t2 = sT[1][r][j];
        if (v2 > v || (v2 == v && t2 < t)) { v = v2; t = t2; }
        nidx[(p + r * 2048) * NS + j] = (v == -INFINITY) ? -1 : t;
    }
}

// ---------------- fallback kernel (small ws): fused ksample ---------------
__global__ __launch_bounds__(256, 2) void ksample(
        const __bf16* __restrict__ xh, const __bf16* __restrict__ xl,
        const float* __restrict__ sqv,
        float* __restrict__ pV, int* __restrict__ pI) {
    const int lane  = threadIdx.x & 63;
    const int chunk = (blockIdx.x << 2) + (threadIdx.x >> 6);
    const int grp   = blockIdx.y;
    const int rlo = lane & 15;
    const int khi = lane >> 4;

    const int afr = grp * 8 + (rlo >> 1) + ((rlo & 1) << 11);
    v8bf ah[4], al[4];
#pragma unroll
    for (int ks = 0; ks < 4; ++ks) {
        const size_t off = (size_t)afr * DIM + ks * 32 + khi * 8;
        ah[ks] = *(const v8bf*)(xh + off);
        al[ks] = *(const v8bf*)(xl + off);
    }
    const int base = grp * 8 + khi * 2;
    float sqA[4];
    sqA[0] = sqv[base];
    sqA[1] = sqv[base + 2048];
    sqA[2] = sqv[base + 1];
    sqA[3] = sqv[base + 2049];
    const uint32_t P0 = (uint32_t)base;
    const uint32_t P1 = (uint32_t)(base + 1);

    float    bestV[4][NS];
    uint32_t bestP[4];
#pragma unroll
    for (int q = 0; q < 4; ++q) {
        bestP[q] = 0u;
#pragma unroll
        for (int j = 0; j < NS; ++j) bestV[q][j] = -INFINITY;
    }
    const int tcol0 = chunk * 256 + rlo;

    v8bf bhn[4], bln[4];
    float sqn;
    {
        const size_t boff = (size_t)tcol0 * DIM + khi * 8;
#pragma unroll
        for (int ks = 0; ks < 4; ++ks) {
            bhn[ks] = *(const v8bf*)(xh + boff + ks * 32);
            bln[ks] = *(const v8bf*)(xl + boff + ks * 32);
        }
        sqn = sqv[tcol0];
    }

#pragma unroll 1
    for (int cg = 0; cg < 16; ++cg) {
        v8bf bhc[4], blc[4];
#pragma unroll
        for (int ks = 0; ks < 4; ++ks) { bhc[ks] = bhn[ks]; blc[ks] = bln[ks]; }
        const float sqB = sqn;
        const int tcol = tcol0 + cg * 16;
        if (cg < 15) {
            const size_t boff = (size_t)(tcol + 16) * DIM + khi * 8;
#pragma unroll
            for (int ks = 0; ks < 4; ++ks) {
                bhn[ks] = *(const v8bf*)(xh + boff + ks * 32);
                bln[ks] = *(const v8bf*)(xl + boff + ks * 32);
            }
            sqn = sqv[tcol + 16];
        }
        v4f acc1 = {0.f, 0.f, 0.f, 0.f};
        v4f acc2 = {0.f, 0.f, 0.f, 0.f};
        v4f acc3 = {0.f, 0.f, 0.f, 0.f};
#pragma unroll
        for (int ks = 0; ks < 4; ++ks) {
            acc1 = __builtin_amdgcn_mfma_f32_16x16x32_bf16(ah[ks], bhc[ks], acc1, 0, 0, 0);
            acc2 = __builtin_amdgcn_mfma_f32_16x16x32_bf16(ah[ks], blc[ks], acc2, 0, 0, 0);
            acc3 = __builtin_amdgcn_mfma_f32_16x16x32_bf16(al[ks], bhc[ks], acc3, 0, 0, 0);
        }
        const int tBlk = tcol >> 3;
        const bool bd0 = (tBlk != grp);
        const bool bd1 = (tBlk != grp + 256);
        float lg[4];
#pragma unroll
        for (int q = 0; q < 4; ++q) {
            float dot = acc1[q] + acc2[q] + acc3[q];
            float d2  = fmaf(-2.0f, dot, sqA[q] + sqB);
            float l1  = __log2f(d2);
            float t2  = fmaf(-0.25f, d2, 1.0f);
            float l2  = __log2f(t2);
            float lw  = fmaf(-43.66827237527655f, l1, -43.32169878499658f * l2);
            bool incl = (d2 < 1.96f) && ((q & 1) ? bd1 : bd0);
            lg[q] = incl ? lw : -INFINITY;
        }
        const uint32_t tB = (uint32_t)tcol;
#pragma unroll
        for (int j = 0; j < NS; ++j) {
            uint32_t L0 = ((P0 * 7u + (uint32_t)j) << 12) + tB;
            uint32_t L1 = ((P1 * 7u + (uint32_t)j) << 12) + tB;
            uint32_t o0, o1, o2, o3;
            threefry2x32(L0, L0 + HALF_CNT, o0, o1);
            threefry2x32(L1, L1 + HALF_CNT, o2, o3);
            float vv[4];
            vv[0] = lg[0] + gumbel_of(o0);
            vv[1] = lg[1] + gumbel_of(o1);
            vv[2] = lg[2] + gumbel_of(o2);
            vv[3] = lg[3] + gumbel_of(o3);
            const uint32_t keep = ~(0xFu << (4 * j));
            const uint32_t put  = ((uint32_t)cg) << (4 * j);
#pragma unroll
            for (int q = 0; q < 4; ++q) {
                bool gt = vv[q] > bestV[q][j];
                uint32_t np = (bestP[q] & keep) | put;
                bestV[q][j] = gt ? vv[q] : bestV[q][j];
                bestP[q]    = gt ? np : bestP[q];
            }
        }
    }
#pragma unroll
    for (int q = 0; q < 4; ++q) {
        const int a = base + (q >> 1) + ((q & 1) << 11);
#pragma unroll
        for (int j = 0; j < NS; ++j) {
            float v = bestV[q][j];
            int idx = tcol0 + (int)((bestP[q] >> (4 * j)) & 0xFu) * 16;
#pragma unroll
            for (int m = 1; m < 16; m <<= 1) {
                float v2 = __shfl_xor(v, m, 16);
                int   i2 = __shfl_xor(idx, m, 16);
                if (v2 > v || (v2 == v && i2 < idx)) { v = v2; idx = i2; }
            }
            if (rlo == 0) {
                size_t s = ((size_t)a * NS + j) * TCH + chunk;
                pV[s] = v;
                pI[s] = idx;
            }
        }
    }
}

__global__ void kcombine(const float* __restrict__ pV, const int* __restrict__ pI,
                         int* __restrict__ nidx) {
    int s = blockIdx.x * 256 + threadIdx.x;
    if (s >= NROWS * NS) return;
    float bv = -INFINITY;
    int bi = 0x7FFFFFFF;
#pragma unroll
    for (int c = 0; c < TCH; ++c) {
        float v = pV[(size_t)s * TCH + c];
        int idx = pI[(size_t)s * TCH + c];
        if (v > bv || (v == bv && idx < bi)) { bv = v; bi = idx; }
    }
    nidx[s] = (bv == -INFINITY) ? -1 : bi;
}

// ---------------- kernel 4: uniform fallback for invalid rows -------------
__global__ void kfixup(int* __restrict__ nidx) {
    const int i = blockIdx.x;
    if (nidx[(size_t)i * NS] >= 0) return;   // normal case: immediate exit
    const int lane = threadIdx.x;            // 64
    for (int j = 0; j < NS; ++j) {
        float bv = -INFINITY;
        int bi = 0x7FFFFFFF;
        for (int t = lane; t < NROWS; t += 64) {
            uint32_t o0, o1;
            float g;
            if (i < 2048) {
                uint32_t L = (((uint32_t)(i * NS + j)) << 12) + (uint32_t)t;
                threefry2x32(L, L + HALF_CNT, o0, o1);
                g = gumbel_of(o0);
            } else {
                uint32_t L = (((uint32_t)((i - 2048) * NS + j)) << 12) + (uint32_t)t;
                threefry2x32(L, L + HALF_CNT, o0, o1);
                g = gumbel_of(o1);
            }
            if (g > bv) { bv = g; bi = t; }
        }
#pragma unroll
        for (int m = 1; m < 64; m <<= 1) {
            float v2 = __shfl_xor(bv, m, 64);
            int   i2 = __shfl_xor(bi, m, 64);
            if (v2 > bv || (v2 == bv && i2 < bi)) { bv = v2; bi = i2; }
        }
        if (lane == 0) nidx[i * NS + j] = bi;
    }
}

// ---------------- kernel 5: triplet losses --------------------------------
__global__ void kloss(const float* __restrict__ x, const int* __restrict__ nidx,
                      float* __restrict__ loss) {
    int s = blockIdx.x * 256 + threadIdx.x;
    if (s >= NROWS * NS) return;
    int i = s / NS, j = s - i * NS;
    int r = i & (KB - 1), blk = i >> 3;
    int po = (j < r) ? j : j + 1;
    int p = blk * KB + po;
    int n = nidx[s] & (NROWS - 1);      // defensive clamp (no-op when correct)
    const float4* A  = (const float4*)(x + (size_t)i * DIM);
    const float4* P  = (const float4*)(x + (size_t)p * DIM);
    const float4* Ng = (const float4*)(x + (size_t)n * DIM);
    float sap = 0.0f, san = 0.0f;
#pragma unroll 8
    for (int k = 0; k < DIM / 4; ++k) {
        float4 a = A[k], pv = P[k], nv = Ng[k];
        float d;
        d = a.x - pv.x + 1e-6f; sap += d * d;
        d = a.y - pv.y + 1e-6f; sap += d * d;
        d = a.z - pv.z + 1e-6f; sap += d * d;
        d = a.w - pv.w + 1e-6f; sap += d * d;
        d = a.x - nv.x + 1e-6f; san += d * d;
        d = a.y - nv.y + 1e-6f; san += d * d;
        d = a.z - nv.z + 1e-6f; san += d * d;
        d = a.w - nv.w + 1e-6f; san += d * d;
    }
    loss[s] = fmaxf(sqrtf(sap) - sqrtf(san) + 1.0f, 0.0f);
}

// ---------------- kernel 6: mean ------------------------------------------
__global__ void kreduce(const float* __restrict__ loss, float* __restrict__ out) {
    __shared__ float part[4];
    const int tid = threadIdx.x;
    float sum = 0.0f;
    for (int s = tid; s < NROWS * NS; s += 256) sum += loss[s];
#pragma unroll
    for (int m = 32; m > 0; m >>= 1) sum += __shfl_xor(sum, m, 64);
    if ((tid & 63) == 0) part[tid >> 6] = sum;
    __syncthreads();
    if (tid == 0) out[0] = (part[0] + part[1] + part[2] + part[3]) / 28672.0f;
}

extern "C" void kernel_launch(void* const* d_in, const int* in_sizes, int n_in,
                              void* d_out, int out_size, void* d_ws, size_t ws_size,
                              hipStream_t stream) {
    const float* x = (const float*)d_in[0];
    float* out = (float*)d_out;

    uint8_t* w = (uint8_t*)d_ws;
    size_t off = 0;
    auto take = [&](size_t bytes) {
        void* p = w + off;
        off = (off + bytes + 255) & ~(size_t)255;
        return p;
    };
    __bf16* xh   = (__bf16*)take((size_t)NROWS * DIM * 2);
    __bf16* xl   = (__bf16*)take((size_t)NROWS * DIM * 2);
    float*  sqv  = (float*)take((size_t)NROWS * 4);
    int*    nidx = (int*)take((size_t)NROWS * NS * 4);
    float*  loss = (float*)take((size_t)NROWS * NS * 4);
    int*    cnt  = (int*)take((size_t)NPAIR * 4);
    const size_t prefix = off;
    const size_t t16_b = (size_t)NPAIR * 4096 * 2;
    const size_t lgp_b = (size_t)NPAIR * 4096 * 8;
    const size_t NEED_BIG = prefix + ((t16_b + 255) & ~(size_t)255) + lgp_b;

    knorm<<<NROWS, 64, 0, stream>>>(x, xh, xl, sqv);

    if (ws_size >= NEED_BIG) {
        unsigned short* t16 = (unsigned short*)take(t16_b);
        float2*         lgp = (float2*)take(lgp_b);
        hipMemsetAsync(cnt, 0, NPAIR * sizeof(int), stream);
        kdist<<<dim3(TCH / 4, 256), 256, 0, stream>>>(xh, xl, sqv, cnt, t16, lgp);
        kgum<<<NPAIR, 128, 0, stream>>>(cnt, t16, lgp, nidx);
    } else {
        float* pV = (float*)take((size_t)NROWS * NS * TCH * 4);
        int*   pI = (int*)take((size_t)NROWS * NS * TCH * 4);
        ksample<<<dim3(TCH / 4, 256), 256, 0, stream>>>(xh, xl, sqv, pV, pI);
        kcombine<<<(NROWS * NS + 255) / 256, 256, 0, stream>>>(pV, pI, nidx);
    }

    kfixup<<<NROWS, 64, 0, stream>>>(nidx);
    kloss<<<(NROWS * NS + 255) / 256, 256, 0, stream>>>(x, nidx, loss);
    kreduce<<<1, 256, 0, stream>>>(loss, out);
}

// Round 7
// 246.172 us; speedup vs baseline: 1.0576x; 1.0576x over previous
//
#include <hip/hip_runtime.h>
#include <stdint.h>

#define NROWS 4096
#define DIM   128
#define KB    8
#define NS    7            // K-1 negatives per anchor
#define TCH   16           // candidate chunks (256 cands each)
#define NSEG  4            // kgum segments (4 chunks each)
#define NPAIR 2048
#define HALF_CNT 58720256u // (4096*7*4096)/2

typedef __bf16 v8bf __attribute__((ext_vector_type(8)));
typedef float  v4f  __attribute__((ext_vector_type(4)));

__device__ __forceinline__ uint32_t rotl32(uint32_t x, int r) {
    return (x << r) | (x >> (32 - r));
}

// JAX threefry2x32, key = [0, 42], 20 rounds. (c0,c1)=(L, L+HALF_CNT):
// o0 = bits for flat index L, o1 = bits for flat index L+HALF_CNT.
__device__ __forceinline__ void threefry2x32(uint32_t c0, uint32_t c1,
                                             uint32_t& o0, uint32_t& o1) {
    const uint32_t ks0 = 0u;
    const uint32_t ks1 = 42u;
    const uint32_t ks2 = 0x1BD11BDAu ^ ks0 ^ ks1;
    uint32_t x0 = c0 + ks0;
    uint32_t x1 = c1 + ks1;
#define TF_R(r) { x0 += x1; x1 = rotl32(x1, r); x1 ^= x0; }
    TF_R(13) TF_R(15) TF_R(26) TF_R(6)
    x0 += ks1; x1 += ks2 + 1u;
    TF_R(17) TF_R(29) TF_R(16) TF_R(24)
    x0 += ks2; x1 += ks0 + 2u;
    TF_R(13) TF_R(15) TF_R(26) TF_R(6)
    x0 += ks0; x1 += ks1 + 3u;
    TF_R(17) TF_R(29) TF_R(16) TF_R(24)
    x0 += ks1; x1 += ks2 + 4u;
    TF_R(13) TF_R(15) TF_R(26) TF_R(6)
    x0 += ks2; x1 += ks0 + 5u;
#undef TF_R
    o0 = x0; o1 = x1;
}

// gumbel = -ln(-ln(u)), u = f + tiny, via native v_log_f32 (log2)
__device__ __forceinline__ float gumbel_of(uint32_t b) {
    float f = __uint_as_float((b >> 9) | 0x3f800000u) - 1.0f;   // [0,1)
    float u = f + 1.17549435e-38f;
    float l1 = __log2f(u);                    // <= 0
    float inner = -0.69314718055994531f * l1; // -ln(u) >= 0
    float l2 = __log2f(inner);
    return -0.69314718055994531f * l2;
}

// ---------------- kernel 1: normalize -> bf16 hi/lo planes + sq -----------
__global__ void knorm(const float* __restrict__ x, __bf16* __restrict__ xh,
                      __bf16* __restrict__ xl, float* __restrict__ sqv) {
    const int i = blockIdx.x;
    const int t = threadIdx.x;  // 64 threads, 2 elems each
    float2 v = ((const float2*)(x + (size_t)i * DIM))[t];
    float s = v.x * v.x + v.y * v.y;
#pragma unroll
    for (int m = 32; m > 0; m >>= 1) s += __shfl_xor(s, m, 64);
    float norm = sqrtf(s) + 1e-5f;
    float ox = v.x / norm, oy = v.y / norm;
    __bf16 hx = (__bf16)ox, hy = (__bf16)oy;
    float lx = ox - (float)hx, ly = oy - (float)hy;
    union { __bf16 b[2]; uint32_t u; } ph, pl;
    ph.b[0] = hx; ph.b[1] = hy;
    pl.b[0] = (__bf16)lx; pl.b[1] = (__bf16)ly;
    ((uint32_t*)xh)[i * 64 + t] = ph.u;
    ((uint32_t*)xl)[i * 64 + t] = pl.u;
    float s2 = ox * ox + oy * oy;
#pragma unroll
    for (int m = 32; m > 0; m >>= 1) s2 += __shfl_xor(s2, m, 64);
    if (t == 0) sqv[i] = s2;
}

// ---------------- kernel 2a: MFMA dists -> per-(pair,chunk) regions -------
// Each (pair,chunk) region (256 slots) is owned by exactly one 16-lane
// group, so a register running count replaces the global atomic. Appends
// are contiguous; final count stored once at the end.
__global__ __launch_bounds__(256, 3) void kdist(
        const __bf16* __restrict__ xh, const __bf16* __restrict__ xl,
        const float* __restrict__ sqv,
        int* __restrict__ cnt, unsigned short* __restrict__ t16,
        float2* __restrict__ lgp) {
    const int lane  = threadIdx.x & 63;
    const int chunk = (blockIdx.x << 2) + (threadIdx.x >> 6);   // 0..15
    const int grp   = blockIdx.y;   // 0..255
    const int rlo = lane & 15;
    const int khi = lane >> 4;
    const unsigned int below = (1u << rlo) - 1u;

    const int afr = grp * 8 + (rlo >> 1) + ((rlo & 1) << 11);
    v8bf ah[4], al[4];
#pragma unroll
    for (int ks = 0; ks < 4; ++ks) {
        const size_t off = (size_t)afr * DIM + ks * 32 + khi * 8;
        ah[ks] = *(const v8bf*)(xh + off);
        al[ks] = *(const v8bf*)(xl + off);
    }

    const int base = grp * 8 + khi * 2;   // pairA = base, pairB = base+1
    float sqA[4];
    sqA[0] = sqv[base];
    sqA[1] = sqv[base + 2048];
    sqA[2] = sqv[base + 1];
    sqA[3] = sqv[base + 2049];

    const int rbA = ((base)     * 16 + chunk) << 8;   // region base, pair A
    const int rbB = ((base + 1) * 16 + chunk) << 8;   // region base, pair B
    unsigned int cA = 0, cB = 0;                      // uniform in 16-group

    const int tcol0 = chunk * 256 + rlo;

    v8bf bhn[4], bln[4];
    float sqn;
    {
        const size_t boff = (size_t)tcol0 * DIM + khi * 8;
#pragma unroll
        for (int ks = 0; ks < 4; ++ks) {
            bhn[ks] = *(const v8bf*)(xh + boff + ks * 32);
            bln[ks] = *(const v8bf*)(xl + boff + ks * 32);
        }
        sqn = sqv[tcol0];
    }

#pragma unroll 1
    for (int cg = 0; cg < 16; ++cg) {
        v8bf bhc[4], blc[4];
#pragma unroll
        for (int ks = 0; ks < 4; ++ks) { bhc[ks] = bhn[ks]; blc[ks] = bln[ks]; }
        const float sqB = sqn;
        const int tcol = tcol0 + cg * 16;

        if (cg < 15) {
            const size_t boff = (size_t)(tcol + 16) * DIM + khi * 8;
#pragma unroll
            for (int ks = 0; ks < 4; ++ks) {
                bhn[ks] = *(const v8bf*)(xh + boff + ks * 32);
                bln[ks] = *(const v8bf*)(xl + boff + ks * 32);
            }
            sqn = sqv[tcol + 16];
        }

        v4f acc1 = {0.f, 0.f, 0.f, 0.f};
        v4f acc2 = {0.f, 0.f, 0.f, 0.f};
        v4f acc3 = {0.f, 0.f, 0.f, 0.f};
#pragma unroll
        for (int ks = 0; ks < 4; ++ks) {
            acc1 = __builtin_amdgcn_mfma_f32_16x16x32_bf16(ah[ks], bhc[ks], acc1, 0, 0, 0);
            acc2 = __builtin_amdgcn_mfma_f32_16x16x32_bf16(ah[ks], blc[ks], acc2, 0, 0, 0);
            acc3 = __builtin_amdgcn_mfma_f32_16x16x32_bf16(al[ks], bhc[ks], acc3, 0, 0, 0);
        }

        const int tBlk = tcol >> 3;
        const bool bd0 = (tBlk != grp);
        const bool bd1 = (tBlk != grp + 256);

        float lg[4];
        bool  ic[4];
#pragma unroll
        for (int q = 0; q < 4; ++q) {
            float dot = acc1[q] + acc2[q] + acc3[q];
            float d2  = fmaf(-2.0f, dot, sqA[q] + sqB);
            float l1  = __log2f(d2);
            float t2  = fmaf(-0.25f, d2, 1.0f);
            float l2  = __log2f(t2);
            float lw  = fmaf(-43.66827237527655f, l1, -43.32169878499658f * l2);
            bool incl = (d2 < 1.96f) && ((q & 1) ? bd1 : bd0);
            ic[q] = incl;
            lg[q] = incl ? lw : -INFINITY;
        }

        const bool uA = ic[0] | ic[1];
        const bool uB = ic[2] | ic[3];
        unsigned long long ballA = __ballot(uA);
        unsigned long long ballB = __ballot(uB);
        unsigned int subA = (unsigned int)((ballA >> (khi * 16)) & 0xFFFFull);
        unsigned int subB = (unsigned int)((ballB >> (khi * 16)) & 0xFFFFull);
        if (uA) {
            int slot = rbA + (int)cA + __popc(subA & below);
            t16[slot] = (unsigned short)tcol;
            lgp[slot] = make_float2(lg[0], lg[1]);
        }
        if (uB) {
            int slot = rbB + (int)cB + __popc(subB & below);
            t16[slot] = (unsigned short)tcol;
            lgp[slot] = make_float2(lg[2], lg[3]);
        }
        cA += (unsigned int)__popc(subA);
        cB += (unsigned int)__popc(subB);
    }

    if (rlo == 0) {
        cnt[base * 16 + chunk]       = (int)cA;
        cnt[(base + 1) * 16 + chunk] = (int)cB;
    }
}

// ---------------- kernel 2b: gumbel argmax, lane = (entry-octet, j) -------
// Block = pair (2048 blocks x 256 thr); wave w = segment of 4 chunks.
// Lanes 0-7 share one entry: j = lane&7 computes that entry's sample-j
// chain (j=7 slot idles to -inf). Per-lane state = 4 values -> no spill;
// parallelism is cross-lane, which the compiler cannot serialize away.
// Total order (v greater)||(v equal && t smaller) -> order-independent.
__global__ __launch_bounds__(256, 8) void kgum(
        const int* __restrict__ cnt, const unsigned short* __restrict__ t16,
        const float2* __restrict__ lgp,
        float* __restrict__ pV, int* __restrict__ pI) {
    const int p    = blockIdx.x;
    const int tid  = threadIdx.x;
    const int seg  = tid >> 6;      // 0..3
    const int lane = tid & 63;
    const int j    = lane & 7;
    const int eo   = lane >> 3;     // entry-octet slot 0..7
    const bool jv  = (j < 7);
    const uint32_t pb = ((uint32_t)p * 7u) << 12;

    float bvA = -INFINITY, bvB = -INFINITY;
    int   btA = 0x7FFFFFFF, btB = 0x7FFFFFFF;

#pragma unroll 1
    for (int c = seg * 4; c < seg * 4 + 4; ++c) {
        const int n  = cnt[p * 16 + c];
        const int rb = (p * 16 + c) << 8;
#pragma unroll 1
        for (int e = eo; e < n; e += 8) {
            const uint32_t t = t16[rb + e];
            const float2 lg  = lgp[rb + e];
            const uint32_t L = pb + ((uint32_t)j << 12) + t;
            uint32_t o0, o1;
            threefry2x32(L, L + HALF_CNT, o0, o1);
            float vA = (jv ? lg.x : -INFINITY) + gumbel_of(o0);
            float vB = (jv ? lg.y : -INFINITY) + gumbel_of(o1);
            const int ti = (int)t;
            if (vA > bvA || (vA == bvA && ti < btA)) { bvA = vA; btA = ti; }
            if (vB > bvB || (vB == bvB && ti < btB)) { bvB = vB; btB = ti; }
        }
    }

    // reduce across entry-octet slots (xor masks 8,16,32)
#pragma unroll
    for (int m = 8; m < 64; m <<= 1) {
        float v2 = __shfl_xor(bvA, m, 64);
        int   t2 = __shfl_xor(btA, m, 64);
        if (v2 > bvA || (v2 == bvA && t2 < btA)) { bvA = v2; btA = t2; }
        v2 = __shfl_xor(bvB, m, 64);
        t2 = __shfl_xor(btB, m, 64);
        if (v2 > bvB || (v2 == bvB && t2 < btB)) { bvB = v2; btB = t2; }
    }

    if (lane < NS) {
        size_t s0 = ((size_t)p * NS + lane) * NSEG + seg;
        pV[s0] = bvA; pI[s0] = btA;
        size_t s1 = ((size_t)(p + 2048) * NS + lane) * NSEG + seg;
        pV[s1] = bvB; pI[s1] = btB;
    }
}

// ---------------- kernel 3: combine partials -> n_idx ---------------------
// bv == -inf  <=>  no included candidate for row (== reference's invalid row)
__global__ void kcombine(const float* __restrict__ pV, const int* __restrict__ pI,
                         int* __restrict__ nidx, int nc) {
    int s = blockIdx.x * 256 + threadIdx.x;
    if (s >= NROWS * NS) return;
    float bv = -INFINITY;
    int bi = 0x7FFFFFFF;
    for (int c = 0; c < nc; ++c) {
        float v = pV[(size_t)s * nc + c];
        int idx = pI[(size_t)s * nc + c];
        if (v > bv || (v == bv && idx < bi)) { bv = v; bi = idx; }
    }
    nidx[s] = (bv == -INFINITY) ? -1 : bi;
}

// ---------------- fallback kernel (small ws): fused ksample ---------------
__global__ __launch_bounds__(256, 2) void ksample(
        const __bf16* __restrict__ xh, const __bf16* __restrict__ xl,
        const float* __restrict__ sqv,
        float* __restrict__ pV, int* __restrict__ pI) {
    const int lane  = threadIdx.x & 63;
    const int chunk = (blockIdx.x << 2) + (threadIdx.x >> 6);
    const int grp   = blockIdx.y;
    const int rlo = lane & 15;
    const int khi = lane >> 4;

    const int afr = grp * 8 + (rlo >> 1) + ((rlo & 1) << 11);
    v8bf ah[4], al[4];
#pragma unroll
    for (int ks = 0; ks < 4; ++ks) {
        const size_t off = (size_t)afr * DIM + ks * 32 + khi * 8;
        ah[ks] = *(const v8bf*)(xh + off);
        al[ks] = *(const v8bf*)(xl + off);
    }
    const int base = grp * 8 + khi * 2;
    float sqA[4];
    sqA[0] = sqv[base];
    sqA[1] = sqv[base + 2048];
    sqA[2] = sqv[base + 1];
    sqA[3] = sqv[base + 2049];
    const uint32_t P0 = (uint32_t)base;
    const uint32_t P1 = (uint32_t)(base + 1);

    float    bestV[4][NS];
    uint32_t bestP[4];
#pragma unroll
    for (int q = 0; q < 4; ++q) {
        bestP[q] = 0u;
#pragma unroll
        for (int j = 0; j < NS; ++j) bestV[q][j] = -INFINITY;
    }
    const int tcol0 = chunk * 256 + rlo;

    v8bf bhn[4], bln[4];
    float sqn;
    {
        const size_t boff = (size_t)tcol0 * DIM + khi * 8;
#pragma unroll
        for (int ks = 0; ks < 4; ++ks) {
            bhn[ks] = *(const v8bf*)(xh + boff + ks * 32);
            bln[ks] = *(const v8bf*)(xl + boff + ks * 32);
        }
        sqn = sqv[tcol0];
    }

#pragma unroll 1
    for (int cg = 0; cg < 16; ++cg) {
        v8bf bhc[4], blc[4];
#pragma unroll
        for (int ks = 0; ks < 4; ++ks) { bhc[ks] = bhn[ks]; blc[ks] = bln[ks]; }
        const float sqB = sqn;
        const int tcol = tcol0 + cg * 16;
        if (cg < 15) {
            const size_t boff = (size_t)(tcol + 16) * DIM + khi * 8;
#pragma unroll
            for (int ks = 0; ks < 4; ++ks) {
                bhn[ks] = *(const v8bf*)(xh + boff + ks * 32);
                bln[ks] = *(const v8bf*)(xl + boff + ks * 32);
            }
            sqn = sqv[tcol + 16];
        }
        v4f acc1 = {0.f, 0.f, 0.f, 0.f};
        v4f acc2 = {0.f, 0.f, 0.f, 0.f};
        v4f acc3 = {0.f, 0.f, 0.f, 0.f};
#pragma unroll
        for (int ks = 0; ks < 4; ++ks) {
            acc1 = __builtin_amdgcn_mfma_f32_16x16x32_bf16(ah[ks], bhc[ks], acc1, 0, 0, 0);
            acc2 = __builtin_amdgcn_mfma_f32_16x16x32_bf16(ah[ks], blc[ks], acc2, 0, 0, 0);
            acc3 = __builtin_amdgcn_mfma_f32_16x16x32_bf16(al[ks], bhc[ks], acc3, 0, 0, 0);
        }
        const int tBlk = tcol >> 3;
        const bool bd0 = (tBlk != grp);
        const bool bd1 = (tBlk != grp + 256);
        float lg[4];
#pragma unroll
        for (int q = 0; q < 4; ++q) {
            float dot = acc1[q] + acc2[q] + acc3[q];
            float d2  = fmaf(-2.0f, dot, sqA[q] + sqB);
            float l1  = __log2f(d2);
            float t2  = fmaf(-0.25f, d2, 1.0f);
            float l2  = __log2f(t2);
            float lw  = fmaf(-43.66827237527655f, l1, -43.32169878499658f * l2);
            bool incl = (d2 < 1.96f) && ((q & 1) ? bd1 : bd0);
            lg[q] = incl ? lw : -INFINITY;
        }
        const uint32_t tB = (uint32_t)tcol;
#pragma unroll
        for (int j = 0; j < NS; ++j) {
            uint32_t L0 = ((P0 * 7u + (uint32_t)j) << 12) + tB;
            uint32_t L1 = ((P1 * 7u + (uint32_t)j) << 12) + tB;
            uint32_t o0, o1, o2, o3;
            threefry2x32(L0, L0 + HALF_CNT, o0, o1);
            threefry2x32(L1, L1 + HALF_CNT, o2, o3);
            float vv[4];
            vv[0] = lg[0] + gumbel_of(o0);
            vv[1] = lg[1] + gumbel_of(o1);
            vv[2] = lg[2] + gumbel_of(o2);
            vv[3] = lg[3] + gumbel_of(o3);
            const uint32_t keep = ~(0xFu << (4 * j));
            const uint32_t put  = ((uint32_t)cg) << (4 * j);
#pragma unroll
            for (int q = 0; q < 4; ++q) {
                bool gt = vv[q] > bestV[q][j];
                uint32_t np = (bestP[q] & keep) | put;
                bestV[q][j] = gt ? vv[q] : bestV[q][j];
                bestP[q]    = gt ? np : bestP[q];
            }
        }
    }
#pragma unroll
    for (int q = 0; q < 4; ++q) {
        const int a = base + (q >> 1) + ((q & 1) << 11);
#pragma unroll
        for (int j = 0; j < NS; ++j) {
            float v = bestV[q][j];
            int idx = tcol0 + (int)((bestP[q] >> (4 * j)) & 0xFu) * 16;
#pragma unroll
            for (int m = 1; m < 16; m <<= 1) {
                float v2 = __shfl_xor(v, m, 16);
                int   i2 = __shfl_xor(idx, m, 16);
                if (v2 > v || (v2 == v && i2 < idx)) { v = v2; idx = i2; }
            }
            if (rlo == 0) {
                size_t s = ((size_t)a * NS + j) * TCH + chunk;
                pV[s] = v;
                pI[s] = idx;
            }
        }
    }
}

// ---------------- kernel 4: uniform fallback for invalid rows -------------
__global__ void kfixup(int* __restrict__ nidx) {
    const int i = blockIdx.x;
    if (nidx[(size_t)i * NS] >= 0) return;   // normal case: immediate exit
    const int lane = threadIdx.x;            // 64
    for (int j = 0; j < NS; ++j) {
        float bv = -INFINITY;
        int bi = 0x7FFFFFFF;
        for (int t = lane; t < NROWS; t += 64) {
            uint32_t o0, o1;
            float g;
            if (i < 2048) {
                uint32_t L = (((uint32_t)(i * NS + j)) << 12) + (uint32_t)t;
                threefry2x32(L, L + HALF_CNT, o0, o1);
                g = gumbel_of(o0);
            } else {
                uint32_t L = (((uint32_t)((i - 2048) * NS + j)) << 12) + (uint32_t)t;
                threefry2x32(L, L + HALF_CNT, o0, o1);
                g = gumbel_of(o1);
            }
            if (g > bv) { bv = g; bi = t; }
        }
#pragma unroll
        for (int m = 1; m < 64; m <<= 1) {
            float v2 = __shfl_xor(bv, m, 64);
            int   i2 = __shfl_xor(bi, m, 64);
            if (v2 > bv || (v2 == bv && i2 < bi)) { bv = v2; bi = i2; }
        }
        if (lane == 0) nidx[i * NS + j] = bi;
    }
}

// ---------------- kernel 5: triplet losses --------------------------------
__global__ void kloss(const float* __restrict__ x, const int* __restrict__ nidx,
                      float* __restrict__ loss) {
    int s = blockIdx.x * 256 + threadIdx.x;
    if (s >= NROWS * NS) return;
    int i = s / NS, j = s - i * NS;
    int r = i & (KB - 1), blk = i >> 3;
    int po = (j < r) ? j : j + 1;
    int p = blk * KB + po;
    int n = nidx[s] & (NROWS - 1);      // defensive clamp (no-op when correct)
    const float4* A  = (const float4*)(x + (size_t)i * DIM);
    const float4* P  = (const float4*)(x + (size_t)p * DIM);
    const float4* Ng = (const float4*)(x + (size_t)n * DIM);
    float sap = 0.0f, san = 0.0f;
#pragma unroll 8
    for (int k = 0; k < DIM / 4; ++k) {
        float4 a = A[k], pv = P[k], nv = Ng[k];
        float d;
        d = a.x - pv.x + 1e-6f; sap += d * d;
        d = a.y - pv.y + 1e-6f; sap += d * d;
        d = a.z - pv.z + 1e-6f; sap += d * d;
        d = a.w - pv.w + 1e-6f; sap += d * d;
        d = a.x - nv.x + 1e-6f; san += d * d;
        d = a.y - nv.y + 1e-6f; san += d * d;
        d = a.z - nv.z + 1e-6f; san += d * d;
        d = a.w - nv.w + 1e-6f; san += d * d;
    }
    loss[s] = fmaxf(sqrtf(sap) - sqrtf(san) + 1.0f, 0.0f);
}

// ---------------- kernel 6: mean ------------------------------------------
__global__ void kreduce(const float* __restrict__ loss, float* __restrict__ out) {
    __shared__ float part[4];
    const int tid = threadIdx.x;
    float sum = 0.0f;
    for (int s = tid; s < NROWS * NS; s += 256) sum += loss[s];
#pragma unroll
    for (int m = 32; m > 0; m >>= 1) sum += __shfl_xor(sum, m, 64);
    if ((tid & 63) == 0) part[tid >> 6] = sum;
    __syncthreads();
    if (tid == 0) out[0] = (part[0] + part[1] + part[2] + part[3]) / 28672.0f;
}

extern "C" void kernel_launch(void* const* d_in, const int* in_sizes, int n_in,
                              void* d_out, int out_size, void* d_ws, size_t ws_size,
                              hipStream_t stream) {
    const float* x = (const float*)d_in[0];
    float* out = (float*)d_out;

    uint8_t* w = (uint8_t*)d_ws;
    size_t off = 0;
    auto take = [&](size_t bytes) {
        void* p = w + off;
        off = (off + bytes + 255) & ~(size_t)255;
        return p;
    };
    __bf16* xh   = (__bf16*)take((size_t)NROWS * DIM * 2);
    __bf16* xl   = (__bf16*)take((size_t)NROWS * DIM * 2);
    float*  sqv  = (float*)take((size_t)NROWS * 4);
    int*    nidx = (int*)take((size_t)NROWS * NS * 4);
    float*  loss = (float*)take((size_t)NROWS * NS * 4);
    int*    cnt  = (int*)take((size_t)NPAIR * 16 * 4);   // per-(pair,chunk)
    const size_t prefix = off;
    const size_t t16_b = (size_t)NPAIR * 16 * 256 * 2;   // 16.8 MB
    const size_t lgp_b = (size_t)NPAIR * 16 * 256 * 8;   // 67.1 MB
    const size_t pv4_b = (size_t)NROWS * NS * NSEG * 4;  // 0.46 MB
    const size_t NEED_BIG = prefix + ((t16_b + 255) & ~(size_t)255)
                          + ((lgp_b + 255) & ~(size_t)255)
                          + 2 * ((pv4_b + 255) & ~(size_t)255);

    knorm<<<NROWS, 64, 0, stream>>>(x, xh, xl, sqv);

    if (ws_size >= NEED_BIG) {
        unsigned short* t16 = (unsigned short*)take(t16_b);
        float2*         lgp = (float2*)take(lgp_b);
        float*          pV  = (float*)take(pv4_b);
        int*            pI  = (int*)take(pv4_b);
        kdist<<<dim3(TCH / 4, 256), 256, 0, stream>>>(xh, xl, sqv, cnt, t16, lgp);
        kgum<<<NPAIR, 256, 0, stream>>>(cnt, t16, lgp, pV, pI);
        kcombine<<<(NROWS * NS + 255) / 256, 256, 0, stream>>>(pV, pI, nidx, NSEG);
    } else {
        float* pV = (float*)take((size_t)NROWS * NS * TCH * 4);
        int*   pI = (int*)take((size_t)NROWS * NS * TCH * 4);
        ksample<<<dim3(TCH / 4, 256), 256, 0, stream>>>(xh, xl, sqv, pV, pI);
        kcombine<<<(NROWS * NS + 255) / 256, 256, 0, stream>>>(pV, pI, nidx, TCH);
    }

    kfixup<<<NROWS, 64, 0, stream>>>(nidx);
    kloss<<<(NROWS * NS + 255) / 256, 256, 0, stream>>>(x, nidx, loss);
    kreduce<<<1, 256, 0, stream>>>(loss, out);
}

// Round 9
// 206.746 us; speedup vs baseline: 1.2592x; 1.1907x over previous
//
#include <hip/hip_runtime.h>
#include <stdint.h>

#define NROWS 4096
#define DIM   128
#define KB    8
#define NS    7            // K-1 negatives per anchor
#define TCH   16           // candidate chunks (256 cands each)
#define NSEG  4            // kgum segments (4 chunks each)
#define NPAIR 2048
#define HALF_CNT 58720256u // (4096*7*4096)/2

typedef __bf16 v8bf __attribute__((ext_vector_type(8)));
typedef float  v4f  __attribute__((ext_vector_type(4)));

__device__ __forceinline__ uint32_t rotl32(uint32_t x, int r) {
    return (x << r) | (x >> (32 - r));
}

// JAX threefry2x32, key = [0, 42], 20 rounds. (c0,c1)=(L, L+HALF_CNT):
// o0 = bits for flat index L, o1 = bits for flat index L+HALF_CNT.
__device__ __forceinline__ void threefry2x32(uint32_t c0, uint32_t c1,
                                             uint32_t& o0, uint32_t& o1) {
    const uint32_t ks0 = 0u;
    const uint32_t ks1 = 42u;
    const uint32_t ks2 = 0x1BD11BDAu ^ ks0 ^ ks1;
    uint32_t x0 = c0 + ks0;
    uint32_t x1 = c1 + ks1;
#define TF_R(r) { x0 += x1; x1 = rotl32(x1, r); x1 ^= x0; }
    TF_R(13) TF_R(15) TF_R(26) TF_R(6)
    x0 += ks1; x1 += ks2 + 1u;
    TF_R(17) TF_R(29) TF_R(16) TF_R(24)
    x0 += ks2; x1 += ks0 + 2u;
    TF_R(13) TF_R(15) TF_R(26) TF_R(6)
    x0 += ks0; x1 += ks1 + 3u;
    TF_R(17) TF_R(29) TF_R(16) TF_R(24)
    x0 += ks1; x1 += ks2 + 4u;
    TF_R(13) TF_R(15) TF_R(26) TF_R(6)
    x0 += ks2; x1 += ks0 + 5u;
#undef TF_R
    o0 = x0; o1 = x1;
}

// gumbel = -ln(-ln(u)) (used only by the never-fires kfixup + fallback)
__device__ __forceinline__ float gumbel_of(uint32_t b) {
    float f = __uint_as_float((b >> 9) | 0x3f800000u) - 1.0f;   // [0,1)
    float u = f + 1.17549435e-38f;
    float l1 = __log2f(u);
    float inner = -0.69314718055994531f * l1;
    float l2 = __log2f(inner);
    return -0.69314718055994531f * l2;
}

// ---------------- kernel 1: normalize -> bf16 plane + sq ------------------
__global__ void knorm(const float* __restrict__ x, __bf16* __restrict__ xb,
                      float* __restrict__ sqv) {
    const int i = blockIdx.x;
    const int t = threadIdx.x;  // 64 threads, 2 elems each
    float2 v = ((const float2*)(x + (size_t)i * DIM))[t];
    float s = v.x * v.x + v.y * v.y;
#pragma unroll
    for (int m = 32; m > 0; m >>= 1) s += __shfl_xor(s, m, 64);
    float norm = sqrtf(s) + 1e-5f;
    float ox = v.x / norm, oy = v.y / norm;
    union { __bf16 b[2]; uint32_t u; } ph;
    ph.b[0] = (__bf16)ox; ph.b[1] = (__bf16)oy;
    ((uint32_t*)xb)[i * 64 + t] = ph.u;
    float s2 = ox * ox + oy * oy;
#pragma unroll
    for (int m = 32; m > 0; m >>= 1) s2 += __shfl_xor(s2, m, 64);
    if (t == 0) sqv[i] = s2;
}

// ---------------- kernel 2a: MFMA dists -> compacted lists (negwinv) ------
// Per (pair,chunk) 256-slot region owned by one 16-lane group: register
// running count, contiguous appends, no atomics. Stores negwinv = -1/w so
// kgum can use the argmin E/w formulation (one log per sample-chain).
__global__ __launch_bounds__(256, 4) void kdist(
        const __bf16* __restrict__ xb, const float* __restrict__ sqv,
        int* __restrict__ cnt, unsigned short* __restrict__ t16,
        float2* __restrict__ nwp) {
    const int lane  = threadIdx.x & 63;
    const int chunk = (blockIdx.x << 2) + (threadIdx.x >> 6);   // 0..15
    const int grp   = blockIdx.y;   // 0..255
    const int rlo = lane & 15;
    const int khi = lane >> 4;
    const unsigned int below = (1u << rlo) - 1u;

    const int afr = grp * 8 + (rlo >> 1) + ((rlo & 1) << 11);
    v8bf ah[4];
#pragma unroll
    for (int ks = 0; ks < 4; ++ks)
        ah[ks] = *(const v8bf*)(xb + (size_t)afr * DIM + ks * 32 + khi * 8);

    const int base = grp * 8 + khi * 2;   // pairA = base, pairB = base+1
    float sqA[4];
    sqA[0] = sqv[base];
    sqA[1] = sqv[base + 2048];
    sqA[2] = sqv[base + 1];
    sqA[3] = sqv[base + 2049];

    const int rbA = ((base)     * 16 + chunk) << 8;
    const int rbB = ((base + 1) * 16 + chunk) << 8;
    unsigned int cA = 0, cB = 0;          // uniform within 16-group

    const int tcol0 = chunk * 256 + rlo;

    v8bf bhn[4];
    float sqn;
    {
        const size_t boff = (size_t)tcol0 * DIM + khi * 8;
#pragma unroll
        for (int ks = 0; ks < 4; ++ks) bhn[ks] = *(const v8bf*)(xb + boff + ks * 32);
        sqn = sqv[tcol0];
    }

#pragma unroll 1
    for (int cg = 0; cg < 16; ++cg) {
        v8bf bhc[4];
#pragma unroll
        for (int ks = 0; ks < 4; ++ks) bhc[ks] = bhn[ks];
        const float sqB = sqn;
        const int tcol = tcol0 + cg * 16;

        if (cg < 15) {
            const size_t boff = (size_t)(tcol + 16) * DIM + khi * 8;
#pragma unroll
            for (int ks = 0; ks < 4; ++ks) bhn[ks] = *(const v8bf*)(xb + boff + ks * 32);
            sqn = sqv[tcol + 16];
        }

        v4f acc = {0.f, 0.f, 0.f, 0.f};
#pragma unroll
        for (int ks = 0; ks < 4; ++ks)
            acc = __builtin_amdgcn_mfma_f32_16x16x32_bf16(ah[ks], bhc[ks], acc, 0, 0, 0);

        const int tBlk = tcol >> 3;
        const bool bd0 = (tBlk != grp);
        const bool bd1 = (tBlk != grp + 256);

        float nw[4];
        bool  ic[4];
#pragma unroll
        for (int q = 0; q < 4; ++q) {
            float d2  = fmaf(-2.0f, acc[q], sqA[q] + sqB);
            float l1  = __log2f(d2);
            float t2  = fmaf(-0.25f, d2, 1.0f);
            float l2  = __log2f(t2);
            // negwinv = -exp(lg)^-1 : lg_nat = -63 ln(d2) - 62.5 ln(1-d2/4)
            float wiv = exp2f(fmaf(63.0f, l1, 62.5f * l2));
            bool incl = (d2 < 1.96f) && ((q & 1) ? bd1 : bd0);
            ic[q] = incl;
            nw[q] = incl ? -wiv : -INFINITY;
        }

        const bool uA = ic[0] | ic[1];
        const bool uB = ic[2] | ic[3];
        unsigned long long ballA = __ballot(uA);
        unsigned long long ballB = __ballot(uB);
        unsigned int subA = (unsigned int)((ballA >> (khi * 16)) & 0xFFFFull);
        unsigned int subB = (unsigned int)((ballB >> (khi * 16)) & 0xFFFFull);
        if (uA) {
            int slot = rbA + (int)cA + __popc(subA & below);
            t16[slot] = (unsigned short)tcol;
            nwp[slot] = make_float2(nw[0], nw[1]);
        }
        if (uB) {
            int slot = rbB + (int)cB + __popc(subB & below);
            t16[slot] = (unsigned short)tcol;
            nwp[slot] = make_float2(nw[2], nw[3]);
        }
        cA += (unsigned int)__popc(subA);
        cB += (unsigned int)__popc(subB);
    }

    if (rlo == 0) {
        cnt[base * 16 + chunk]       = (int)cA;
        cnt[(base + 1) * 16 + chunk] = (int)cB;
    }
}

// ---------------- kernel 2b: argmin E/w over compacted lists --------------
// Block = pair (2048 x 256); wave = segment of 4 chunks; lane = (eo, j).
// 4 entries per iteration: loads issued up front, 4 independent threefry
// chains explicitly interleaved (ILP-4, ~40 VGPR so no spill pressure).
// key = log2(u) * negwinv  (>0; +inf = excluded);  argmin with tie-break
// (key smaller)||(equal && t smaller) == reference argmax first-index.
#define TFR4(r)                                                         \
    _Pragma("unroll") for (int k = 0; k < 4; ++k) {                     \
        x0[k] += x1[k]; x1[k] = rotl32(x1[k], (r)); x1[k] ^= x0[k];     \
    }
#define INJ4(a, b)                                                      \
    _Pragma("unroll") for (int k = 0; k < 4; ++k) {                     \
        x0[k] += (a); x1[k] += (b);                                     \
    }

__global__ __launch_bounds__(256, 4) void kgum(
        const int* __restrict__ cnt, const unsigned short* __restrict__ t16,
        const float2* __restrict__ nwp,
        float* __restrict__ pV, int* __restrict__ pI) {
    const int p    = blockIdx.x;
    const int tid  = threadIdx.x;
    const int seg  = tid >> 6;      // 0..3
    const int lane = tid & 63;
    const int j    = lane & 7;
    const int eo   = lane >> 3;     // entry-octet slot 0..7
    const bool jv  = (j < 7);
    const uint32_t pb = ((uint32_t)p * 7u + (uint32_t)j) << 12;

    float bkA = INFINITY, bkB = INFINITY;
    int   btA = 0x7FFFFFFF, btB = 0x7FFFFFFF;

#pragma unroll 1
    for (int c = seg * 4; c < seg * 4 + 4; ++c) {
        const int n  = cnt[p * 16 + c];
        const int rb = (p * 16 + c) << 8;
        int e = eo;

#pragma unroll 1
        for (; e + 24 < n; e += 32) {
            uint32_t tt[4];
            float2   nw[4];
#pragma unroll
            for (int k = 0; k < 4; ++k) {
                tt[k] = t16[rb + e + 8 * k];
                nw[k] = nwp[rb + e + 8 * k];
            }
            uint32_t x0[4], x1[4];
#pragma unroll
            for (int k = 0; k < 4; ++k) {
                uint32_t L = pb + tt[k];
                x0[k] = L;
                x1[k] = L + (HALF_CNT + 42u);
            }
            TFR4(13) TFR4(15) TFR4(26) TFR4(6)
            INJ4(42u, 0x1BD11BF0u + 1u)
            TFR4(17) TFR4(29) TFR4(16) TFR4(24)
            INJ4(0x1BD11BF0u, 2u)
            TFR4(13) TFR4(15) TFR4(26) TFR4(6)
            INJ4(0u, 45u)
            TFR4(17) TFR4(29) TFR4(16) TFR4(24)
            INJ4(42u, 0x1BD11BF0u + 4u)
            TFR4(13) TFR4(15) TFR4(26) TFR4(6)
            INJ4(0x1BD11BF0u, 5u)
#pragma unroll
            for (int k = 0; k < 4; ++k) {
                float fA = __uint_as_float((x0[k] >> 9) | 0x3f800000u) - 1.0f;
                float fB = __uint_as_float((x1[k] >> 9) | 0x3f800000u) - 1.0f;
                float l1A = __log2f(fA + 1.17549435e-38f);
                float l1B = __log2f(fB + 1.17549435e-38f);
                float kA = jv ? l1A * nw[k].x : INFINITY;
                float kB = jv ? l1B * nw[k].y : INFINITY;
                const int ti = (int)tt[k];
                if (kA < bkA || (kA == bkA && ti < btA)) { bkA = kA; btA = ti; }
                if (kB < bkB || (kB == bkB && ti < btB)) { bkB = kB; btB = ti; }
            }
        }

        // remainder (1-wide)
#pragma unroll 1
        for (; e < n; e += 8) {
            const uint32_t t = t16[rb + e];
            const float2 nw  = nwp[rb + e];
            const uint32_t L = pb + t;
            uint32_t o0, o1;
            threefry2x32(L, L + HALF_CNT, o0, o1);
            float fA = __uint_as_float((o0 >> 9) | 0x3f800000u) - 1.0f;
            float fB = __uint_as_float((o1 >> 9) | 0x3f800000u) - 1.0f;
            float l1A = __log2f(fA + 1.17549435e-38f);
            float l1B = __log2f(fB + 1.17549435e-38f);
            float kA = jv ? l1A * nw.x : INFINITY;
            float kB = jv ? l1B * nw.y : INFINITY;
            const int ti = (int)t;
            if (kA < bkA || (kA == bkA && ti < btA)) { bkA = kA; btA = ti; }
            if (kB < bkB || (kB == bkB && ti < btB)) { bkB = kB; btB = ti; }
        }
    }

    // reduce across entry-octet slots (xor masks 8,16,32): min-key
#pragma unroll
    for (int m = 8; m < 64; m <<= 1) {
        float v2 = __shfl_xor(bkA, m, 64);
        int   t2 = __shfl_xor(btA, m, 64);
        if (v2 < bkA || (v2 == bkA && t2 < btA)) { bkA = v2; btA = t2; }
        v2 = __shfl_xor(bkB, m, 64);
        t2 = __shfl_xor(btB, m, 64);
        if (v2 < bkB || (v2 == bkB && t2 < btB)) { bkB = v2; btB = t2; }
    }

    if (lane < NS) {
        size_t s0 = ((size_t)p * NS + lane) * NSEG + seg;
        pV[s0] = bkA; pI[s0] = btA;
        size_t s1 = ((size_t)(p + 2048) * NS + lane) * NSEG + seg;
        pV[s1] = bkB; pI[s1] = btB;
    }
}

// ---------------- kernel 3: combine partials (min-key) -> n_idx -----------
// key == +inf  <=>  no included candidate for row (reference invalid row)
__global__ void kcombine(const float* __restrict__ pV, const int* __restrict__ pI,
                         int* __restrict__ nidx, int nc) {
    int s = blockIdx.x * 256 + threadIdx.x;
    if (s >= NROWS * NS) return;
    float bv = INFINITY;
    int bi = 0x7FFFFFFF;
    for (int c = 0; c < nc; ++c) {
        float v = pV[(size_t)s * nc + c];
        int idx = pI[(size_t)s * nc + c];
        if (v < bv || (v == bv && idx < bi)) { bv = v; bi = idx; }
    }
    nidx[s] = (bv == INFINITY) ? -1 : bi;
}

// ---------------- fallback (small ws): fused sample, min-key partials -----
__global__ __launch_bounds__(256, 2) void ksample(
        const __bf16* __restrict__ xb, const float* __restrict__ sqv,
        float* __restrict__ pV, int* __restrict__ pI) {
    const int lane  = threadIdx.x & 63;
    const int chunk = (blockIdx.x << 2) + (threadIdx.x >> 6);
    const int grp   = blockIdx.y;
    const int rlo = lane & 15;
    const int khi = lane >> 4;

    const int afr = grp * 8 + (rlo >> 1) + ((rlo & 1) << 11);
    v8bf ah[4];
#pragma unroll
    for (int ks = 0; ks < 4; ++ks)
        ah[ks] = *(const v8bf*)(xb + (size_t)afr * DIM + ks * 32 + khi * 8);
    const int base = grp * 8 + khi * 2;
    float sqA[4];
    sqA[0] = sqv[base];
    sqA[1] = sqv[base + 2048];
    sqA[2] = sqv[base + 1];
    sqA[3] = sqv[base + 2049];
    const uint32_t P0 = (uint32_t)base;
    const uint32_t P1 = (uint32_t)(base + 1);

    float    bestV[4][NS];
    uint32_t bestP[4];
#pragma unroll
    for (int q = 0; q < 4; ++q) {
        bestP[q] = 0u;
#pragma unroll
        for (int j = 0; j < NS; ++j) bestV[q][j] = INFINITY;
    }
    const int tcol0 = chunk * 256 + rlo;

    v8bf bhn[4];
    float sqn;
    {
        const size_t boff = (size_t)tcol0 * DIM + khi * 8;
#pragma unroll
        for (int ks = 0; ks < 4; ++ks) bhn[ks] = *(const v8bf*)(xb + boff + ks * 32);
        sqn = sqv[tcol0];
    }

#pragma unroll 1
    for (int cg = 0; cg < 16; ++cg) {
        v8bf bhc[4];
#pragma unroll
        for (int ks = 0; ks < 4; ++ks) bhc[ks] = bhn[ks];
        const float sqB = sqn;
        const int tcol = tcol0 + cg * 16;
        if (cg < 15) {
            const size_t boff = (size_t)(tcol + 16) * DIM + khi * 8;
#pragma unroll
            for (int ks = 0; ks < 4; ++ks) bhn[ks] = *(const v8bf*)(xb + boff + ks * 32);
            sqn = sqv[tcol + 16];
        }
        v4f acc = {0.f, 0.f, 0.f, 0.f};
#pragma unroll
        for (int ks = 0; ks < 4; ++ks)
            acc = __builtin_amdgcn_mfma_f32_16x16x32_bf16(ah[ks], bhc[ks], acc, 0, 0, 0);
        const int tBlk = tcol >> 3;
        const bool bd0 = (tBlk != grp);
        const bool bd1 = (tBlk != grp + 256);
        float nw[4];
#pragma unroll
        for (int q = 0; q < 4; ++q) {
            float d2  = fmaf(-2.0f, acc[q], sqA[q] + sqB);
            float l1  = __log2f(d2);
            float t2  = fmaf(-0.25f, d2, 1.0f);
            float l2  = __log2f(t2);
            float wiv = exp2f(fmaf(63.0f, l1, 62.5f * l2));
            bool incl = (d2 < 1.96f) && ((q & 1) ? bd1 : bd0);
            nw[q] = incl ? -wiv : -INFINITY;
        }
        const uint32_t tB = (uint32_t)tcol;
#pragma unroll
        for (int j = 0; j < NS; ++j) {
            uint32_t L0 = ((P0 * 7u + (uint32_t)j) << 12) + tB;
            uint32_t L1 = ((P1 * 7u + (uint32_t)j) << 12) + tB;
            uint32_t o0, o1, o2, o3;
            threefry2x32(L0, L0 + HALF_CNT, o0, o1);
            threefry2x32(L1, L1 + HALF_CNT, o2, o3);
            float vv[4];
            vv[0] = __log2f(__uint_as_float((o0 >> 9) | 0x3f800000u) - 1.0f + 1.17549435e-38f) * nw[0];
            vv[1] = __log2f(__uint_as_float((o1 >> 9) | 0x3f800000u) - 1.0f + 1.17549435e-38f) * nw[1];
            vv[2] = __log2f(__uint_as_float((o2 >> 9) | 0x3f800000u) - 1.0f + 1.17549435e-38f) * nw[2];
            vv[3] = __log2f(__uint_as_float((o3 >> 9) | 0x3f800000u) - 1.0f + 1.17549435e-38f) * nw[3];
            const uint32_t keep = ~(0xFu << (4 * j));
            const uint32_t put  = ((uint32_t)cg) << (4 * j);
#pragma unroll
            for (int q = 0; q < 4; ++q) {
                bool lt = vv[q] < bestV[q][j];
                uint32_t np = (bestP[q] & keep) | put;
                bestV[q][j] = lt ? vv[q] : bestV[q][j];
                bestP[q]    = lt ? np : bestP[q];
            }
        }
    }
#pragma unroll
    for (int q = 0; q < 4; ++q) {
        const int a = base + (q >> 1) + ((q & 1) << 11);
#pragma unroll
        for (int j = 0; j < NS; ++j) {
            float v = bestV[q][j];
            int idx = tcol0 + (int)((bestP[q] >> (4 * j)) & 0xFu) * 16;
#pragma unroll
            for (int m = 1; m < 16; m <<= 1) {
                float v2 = __shfl_xor(v, m, 16);
                int   i2 = __shfl_xor(idx, m, 16);
                if (v2 < v || (v2 == v && i2 < idx)) { v = v2; idx = i2; }
            }
            if (rlo == 0) {
                size_t s = ((size_t)a * NS + j) * TCH + chunk;
                pV[s] = v;
                pI[s] = idx;
            }
        }
    }
}

// ---------------- kernel 4: uniform fallback for invalid rows -------------
__global__ void kfixup(int* __restrict__ nidx) {
    const int i = blockIdx.x;
    if (nidx[(size_t)i * NS] >= 0) return;   // normal case: immediate exit
    const int lane = threadIdx.x;            // 64
    for (int j = 0; j < NS; ++j) {
        float bv = -INFINITY;
        int bi = 0x7FFFFFFF;
        for (int t = lane; t < NROWS; t += 64) {
            uint32_t o0, o1;
            float g;
            if (i < 2048) {
                uint32_t L = (((uint32_t)(i * NS + j)) << 12) + (uint32_t)t;
                threefry2x32(L, L + HALF_CNT, o0, o1);
                g = gumbel_of(o0);
            } else {
                uint32_t L = (((uint32_t)((i - 2048) * NS + j)) << 12) + (uint32_t)t;
                threefry2x32(L, L + HALF_CNT, o0, o1);
                g = gumbel_of(o1);
            }
            if (g > bv) { bv = g; bi = t; }
        }
#pragma unroll
        for (int m = 1; m < 64; m <<= 1) {
            float v2 = __shfl_xor(bv, m, 64);
            int   i2 = __shfl_xor(bi, m, 64);
            if (v2 > bv || (v2 == bv && i2 < bi)) { bv = v2; bi = i2; }
        }
        if (lane == 0) nidx[i * NS + j] = bi;
    }
}

// ---------------- kernel 5: triplet losses --------------------------------
__global__ void kloss(const float* __restrict__ x, const int* __restrict__ nidx,
                      float* __restrict__ loss) {
    int s = blockIdx.x * 256 + threadIdx.x;
    if (s >= NROWS * NS) return;
    int i = s / NS, j = s - i * NS;
    int r = i & (KB - 1), blk = i >> 3;
    int po = (j < r) ? j : j + 1;
    int p = blk * KB + po;
    int n = nidx[s] & (NROWS - 1);      // defensive clamp (no-op when correct)
    const float4* A  = (const float4*)(x + (size_t)i * DIM);
    const float4* P  = (const float4*)(x + (size_t)p * DIM);
    const float4* Ng = (const float4*)(x + (size_t)n * DIM);
    float sap = 0.0f, san = 0.0f;
#pragma unroll 8
    for (int k = 0; k < DIM / 4; ++k) {
        float4 a = A[k], pv = P[k], nv = Ng[k];
        float d;
        d = a.x - pv.x + 1e-6f; sap += d * d;
        d = a.y - pv.y + 1e-6f; sap += d * d;
        d = a.z - pv.z + 1e-6f; sap += d * d;
        d = a.w - pv.w + 1e-6f; sap += d * d;
        d = a.x - nv.x + 1e-6f; san += d * d;
        d = a.y - nv.y + 1e-6f; san += d * d;
        d = a.z - nv.z + 1e-6f; san += d * d;
        d = a.w - nv.w + 1e-6f; san += d * d;
    }
    loss[s] = fmaxf(sqrtf(sap) - sqrtf(san) + 1.0f, 0.0f);
}

// ---------------- kernel 6: mean ------------------------------------------
__global__ void kreduce(const float* __restrict__ loss, float* __restrict__ out) {
    __shared__ float part[4];
    const int tid = threadIdx.x;
    float sum = 0.0f;
    for (int s = tid; s < NROWS * NS; s += 256) sum += loss[s];
#pragma unroll
    for (int m = 32; m > 0; m >>= 1) sum += __shfl_xor(sum, m, 64);
    if ((tid & 63) == 0) part[tid >> 6] = sum;
    __syncthreads();
    if (tid == 0) out[0] = (part[0] + part[1] + part[2] + part[3]) / 28672.0f;
}

extern "C" void kernel_launch(void* const* d_in, const int* in_sizes, int n_in,
                              void* d_out, int out_size, void* d_ws, size_t ws_size,
                              hipStream_t stream) {
    const float* x = (const float*)d_in[0];
    float* out = (float*)d_out;

    uint8_t* w = (uint8_t*)d_ws;
    size_t off = 0;
    auto take = [&](size_t bytes) {
        void* p = w + off;
        off = (off + bytes + 255) & ~(size_t)255;
        return p;
    };
    __bf16* xb   = (__bf16*)take((size_t)NROWS * DIM * 2);
    float*  sqv  = (float*)take((size_t)NROWS * 4);
    int*    nidx = (int*)take((size_t)NROWS * NS * 4);
    float*  loss = (float*)take((size_t)NROWS * NS * 4);
    int*    cnt  = (int*)take((size_t)NPAIR * 16 * 4);   // per-(pair,chunk)
    const size_t prefix = off;
    const size_t t16_b = (size_t)NPAIR * 16 * 256 * 2;   // 16.8 MB
    const size_t nwp_b = (size_t)NPAIR * 16 * 256 * 8;   // 67.1 MB
    const size_t pv4_b = (size_t)NROWS * NS * NSEG * 4;  // 0.46 MB
    const size_t NEED_BIG = prefix + ((t16_b + 255) & ~(size_t)255)
                          + ((nwp_b + 255) & ~(size_t)255)
                          + 2 * ((pv4_b + 255) & ~(size_t)255);

    knorm<<<NROWS, 64, 0, stream>>>(x, xb, sqv);

    if (ws_size >= NEED_BIG) {
        unsigned short* t16 = (unsigned short*)take(t16_b);
        float2*         nwp = (float2*)take(nwp_b);
        float*          pV  = (float*)take(pv4_b);
        int*            pI  = (int*)take(pv4_b);
        kdist<<<dim3(TCH / 4, 256), 256, 0, stream>>>(xb, sqv, cnt, t16, nwp);
        kgum<<<NPAIR, 256, 0, stream>>>(cnt, t16, nwp, pV, pI);
        kcombine<<<(NROWS * NS + 255) / 256, 256, 0, stream>>>(pV, pI, nidx, NSEG);
    } else {
        float* pV = (float*)take((size_t)NROWS * NS * TCH * 4);
        int*   pI = (int*)take((size_t)NROWS * NS * TCH * 4);
        ksample<<<dim3(TCH / 4, 256), 256, 0, stream>>>(xb, sqv, pV, pI);
        kcombine<<<(NROWS * NS + 255) / 256, 256, 0, stream>>>(pV, pI, nidx, TCH);
    }

    kfixup<<<NROWS, 64, 0, stream>>>(nidx);
    kloss<<<(NROWS * NS + 255) / 256, 256, 0, stream>>>(x, nidx, loss);
    kreduce<<<1, 256, 0, stream>>>(loss, out);
}

// Round 10
// 202.001 us; speedup vs baseline: 1.2888x; 1.0235x over previous
//
#include <hip/hip_runtime.h>
#include <stdint.h>

#define NROWS 4096
#define DIM   128
#define KB    8
#define NS    7            // K-1 negatives per anchor
#define TCH   16           // candidate chunks (256 cands each)
#define NSEG  4            // partial-combine groups (4 chunks each)
#define NPAIR 2048
#define HALF_CNT 58720256u // (4096*7*4096)/2

typedef __bf16 v8bf __attribute__((ext_vector_type(8)));
typedef float  v4f  __attribute__((ext_vector_type(4)));

__device__ __forceinline__ uint32_t rotl32(uint32_t x, int r) {
    return (x << r) | (x >> (32 - r));
}

// JAX threefry2x32, key = [0, 42], 20 rounds. (c0,c1)=(L, L+HALF_CNT):
// o0 = bits for flat index L, o1 = bits for flat index L+HALF_CNT.
__device__ __forceinline__ void threefry2x32(uint32_t c0, uint32_t c1,
                                             uint32_t& o0, uint32_t& o1) {
    const uint32_t ks0 = 0u;
    const uint32_t ks1 = 42u;
    const uint32_t ks2 = 0x1BD11BDAu ^ ks0 ^ ks1;
    uint32_t x0 = c0 + ks0;
    uint32_t x1 = c1 + ks1;
#define TF_R(r) { x0 += x1; x1 = rotl32(x1, r); x1 ^= x0; }
    TF_R(13) TF_R(15) TF_R(26) TF_R(6)
    x0 += ks1; x1 += ks2 + 1u;
    TF_R(17) TF_R(29) TF_R(16) TF_R(24)
    x0 += ks2; x1 += ks0 + 2u;
    TF_R(13) TF_R(15) TF_R(26) TF_R(6)
    x0 += ks0; x1 += ks1 + 3u;
    TF_R(17) TF_R(29) TF_R(16) TF_R(24)
    x0 += ks1; x1 += ks2 + 4u;
    TF_R(13) TF_R(15) TF_R(26) TF_R(6)
    x0 += ks2; x1 += ks0 + 5u;
#undef TF_R
    o0 = x0; o1 = x1;
}

// gumbel = -ln(-ln(u)) (used only by the never-fires kfixup + fallback)
__device__ __forceinline__ float gumbel_of(uint32_t b) {
    float f = __uint_as_float((b >> 9) | 0x3f800000u) - 1.0f;   // [0,1)
    float u = f + 1.17549435e-38f;
    float l1 = __log2f(u);
    float inner = -0.69314718055994531f * l1;
    float l2 = __log2f(inner);
    return -0.69314718055994531f * l2;
}

// ---------------- kernel 1: normalize -> bf16 plane + sq ------------------
__global__ void knorm(const float* __restrict__ x, __bf16* __restrict__ xb,
                      float* __restrict__ sqv) {
    const int i = blockIdx.x;
    const int t = threadIdx.x;  // 64 threads, 2 elems each
    float2 v = ((const float2*)(x + (size_t)i * DIM))[t];
    float s = v.x * v.x + v.y * v.y;
#pragma unroll
    for (int m = 32; m > 0; m >>= 1) s += __shfl_xor(s, m, 64);
    float norm = sqrtf(s) + 1e-5f;
    float ox = v.x / norm, oy = v.y / norm;
    union { __bf16 b[2]; uint32_t u; } ph;
    ph.b[0] = (__bf16)ox; ph.b[1] = (__bf16)oy;
    ((uint32_t*)xb)[i * 64 + t] = ph.u;
    float s2 = ox * ox + oy * oy;
#pragma unroll
    for (int m = 32; m > 0; m >>= 1) s2 += __shfl_xor(s2, m, 64);
    if (t == 0) sqv[i] = s2;
}

// ---------------- kernel 2a: MFMA dists -> compacted lists (negwinv) ------
// Per (pair,chunk) 256-slot region owned by one 16-lane group: register
// running count, contiguous appends, no atomics. Stores negwinv = -1/w so
// kgum can use the argmin E/w formulation (one log per sample-chain).
__global__ __launch_bounds__(256, 4) void kdist(
        const __bf16* __restrict__ xb, const float* __restrict__ sqv,
        int* __restrict__ cnt, unsigned short* __restrict__ t16,
        float2* __restrict__ nwp) {
    const int lane  = threadIdx.x & 63;
    const int chunk = (blockIdx.x << 2) + (threadIdx.x >> 6);   // 0..15
    const int grp   = blockIdx.y;   // 0..255
    const int rlo = lane & 15;
    const int khi = lane >> 4;
    const unsigned int below = (1u << rlo) - 1u;

    const int afr = grp * 8 + (rlo >> 1) + ((rlo & 1) << 11);
    v8bf ah[4];
#pragma unroll
    for (int ks = 0; ks < 4; ++ks)
        ah[ks] = *(const v8bf*)(xb + (size_t)afr * DIM + ks * 32 + khi * 8);

    const int base = grp * 8 + khi * 2;   // pairA = base, pairB = base+1
    float sqA[4];
    sqA[0] = sqv[base];
    sqA[1] = sqv[base + 2048];
    sqA[2] = sqv[base + 1];
    sqA[3] = sqv[base + 2049];

    const int rbA = ((base)     * 16 + chunk) << 8;
    const int rbB = ((base + 1) * 16 + chunk) << 8;
    unsigned int cA = 0, cB = 0;          // uniform within 16-group

    const int tcol0 = chunk * 256 + rlo;

    v8bf bhn[4];
    float sqn;
    {
        const size_t boff = (size_t)tcol0 * DIM + khi * 8;
#pragma unroll
        for (int ks = 0; ks < 4; ++ks) bhn[ks] = *(const v8bf*)(xb + boff + ks * 32);
        sqn = sqv[tcol0];
    }

#pragma unroll 1
    for (int cg = 0; cg < 16; ++cg) {
        v8bf bhc[4];
#pragma unroll
        for (int ks = 0; ks < 4; ++ks) bhc[ks] = bhn[ks];
        const float sqB = sqn;
        const int tcol = tcol0 + cg * 16;

        if (cg < 15) {
            const size_t boff = (size_t)(tcol + 16) * DIM + khi * 8;
#pragma unroll
            for (int ks = 0; ks < 4; ++ks) bhn[ks] = *(const v8bf*)(xb + boff + ks * 32);
            sqn = sqv[tcol + 16];
        }

        v4f acc = {0.f, 0.f, 0.f, 0.f};
#pragma unroll
        for (int ks = 0; ks < 4; ++ks)
            acc = __builtin_amdgcn_mfma_f32_16x16x32_bf16(ah[ks], bhc[ks], acc, 0, 0, 0);

        const int tBlk = tcol >> 3;
        const bool bd0 = (tBlk != grp);
        const bool bd1 = (tBlk != grp + 256);

        float nw[4];
        bool  ic[4];
#pragma unroll
        for (int q = 0; q < 4; ++q) {
            float d2  = fmaf(-2.0f, acc[q], sqA[q] + sqB);
            float l1  = __log2f(d2);
            float t2  = fmaf(-0.25f, d2, 1.0f);
            float l2  = __log2f(t2);
            // negwinv = -exp(lg)^-1 : lg_nat = -63 ln(d2) - 62.5 ln(1-d2/4)
            float wiv = exp2f(fmaf(63.0f, l1, 62.5f * l2));
            bool incl = (d2 < 1.96f) && ((q & 1) ? bd1 : bd0);
            ic[q] = incl;
            nw[q] = incl ? -wiv : -INFINITY;
        }

        const bool uA = ic[0] | ic[1];
        const bool uB = ic[2] | ic[3];
        unsigned long long ballA = __ballot(uA);
        unsigned long long ballB = __ballot(uB);
        unsigned int subA = (unsigned int)((ballA >> (khi * 16)) & 0xFFFFull);
        unsigned int subB = (unsigned int)((ballB >> (khi * 16)) & 0xFFFFull);
        if (uA) {
            int slot = rbA + (int)cA + __popc(subA & below);
            t16[slot] = (unsigned short)tcol;
            nwp[slot] = make_float2(nw[0], nw[1]);
        }
        if (uB) {
            int slot = rbB + (int)cB + __popc(subB & below);
            t16[slot] = (unsigned short)tcol;
            nwp[slot] = make_float2(nw[2], nw[3]);
        }
        cA += (unsigned int)__popc(subA);
        cB += (unsigned int)__popc(subB);
    }

    if (rlo == 0) {
        cnt[base * 16 + chunk]       = (int)cA;
        cnt[(base + 1) * 16 + chunk] = (int)cB;
    }
}

// ---------------- kernel 2b: argmin E/w, one WAVE per region --------------
// grid = 8192 blocks x 256: block = 4 consecutive regions (same pair p,
// chunks cgrp*4..+3). Wave = one region (<=256 entries -> bounded tail,
// 32 blocks/CU of TLP). Lane = (entry-octet eo, sample j). 1-deep register
// prefetch hides the list-load latency under the threefry of the current
// entry. Tie-break total order (key smaller)||(equal && t smaller) keeps
// the result order-independent (== reference argmax first-index).
__global__ __launch_bounds__(256, 8) void kgum(
        const int* __restrict__ cnt, const unsigned short* __restrict__ t16,
        const float2* __restrict__ nwp,
        float* __restrict__ pV, int* __restrict__ pI) {
    const int wid  = threadIdx.x >> 6;            // 0..3
    const int rid  = (blockIdx.x << 2) + wid;     // region id 0..32767
    const int p    = rid >> 4;                    // pair
    const int lane = threadIdx.x & 63;
    const int j    = lane & 7;
    const int eo   = lane >> 3;                   // entry-octet slot 0..7
    const bool jv  = (j < 7);
    const uint32_t pb = ((uint32_t)p * 7u + (uint32_t)j) << 12;

    const int n  = cnt[rid];
    const int rb = rid << 8;

    float bkA = INFINITY, bkB = INFINITY;
    int   btA = 0x7FFFFFFF, btB = 0x7FFFFFFF;

    uint32_t tcur = 0;
    float2   nwcur = make_float2(0.f, 0.f);
    if (eo < n) { tcur = t16[rb + eo]; nwcur = nwp[rb + eo]; }

#pragma unroll 1
    for (int e = eo; e < n; e += 8) {
        uint32_t tnx = tcur;
        float2   nwnx = nwcur;
        if (e + 8 < n) { tnx = t16[rb + e + 8]; nwnx = nwp[rb + e + 8]; }

        const uint32_t L = pb + tcur;
        uint32_t o0, o1;
        threefry2x32(L, L + HALF_CNT, o0, o1);
        float fA = __uint_as_float((o0 >> 9) | 0x3f800000u) - 1.0f;
        float fB = __uint_as_float((o1 >> 9) | 0x3f800000u) - 1.0f;
        float l1A = __log2f(fA + 1.17549435e-38f);
        float l1B = __log2f(fB + 1.17549435e-38f);
        float kA = jv ? l1A * nwcur.x : INFINITY;
        float kB = jv ? l1B * nwcur.y : INFINITY;
        const int ti = (int)tcur;
        if (kA < bkA || (kA == bkA && ti < btA)) { bkA = kA; btA = ti; }
        if (kB < bkB || (kB == bkB && ti < btB)) { bkB = kB; btB = ti; }

        tcur = tnx; nwcur = nwnx;
    }

    // reduce across entry-octet slots (xor masks 8,16,32): min-key
#pragma unroll
    for (int m = 8; m < 64; m <<= 1) {
        float v2 = __shfl_xor(bkA, m, 64);
        int   t2 = __shfl_xor(btA, m, 64);
        if (v2 < bkA || (v2 == bkA && t2 < btA)) { bkA = v2; btA = t2; }
        v2 = __shfl_xor(bkB, m, 64);
        t2 = __shfl_xor(btB, m, 64);
        if (v2 < bkB || (v2 == bkB && t2 < btB)) { bkB = v2; btB = t2; }
    }

    // block-level reduction over the 4 same-pair regions -> one partial
    __shared__ float sV[4][2][NS];
    __shared__ int   sT[4][2][NS];
    if (lane < NS) {
        sV[wid][0][lane] = bkA; sT[wid][0][lane] = btA;
        sV[wid][1][lane] = bkB; sT[wid][1][lane] = btB;
    }
    __syncthreads();
    if (threadIdx.x < 2 * NS) {
        const int r = threadIdx.x / NS, jj = threadIdx.x - r * NS;
        float v = sV[0][r][jj];
        int   t = sT[0][r][jj];
#pragma unroll
        for (int w = 1; w < 4; ++w) {
            float v2 = sV[w][r][jj];
            int   t2 = sT[w][r][jj];
            if (v2 < v || (v2 == v && t2 < t)) { v = v2; t = t2; }
        }
        const int cgrp = blockIdx.x & 3;
        size_t s = ((size_t)(p + r * 2048) * NS + jj) * NSEG + cgrp;
        pV[s] = v; pI[s] = t;
    }
}

// ---------------- kernel 3: combine partials (min-key) -> n_idx -----------
// key == +inf  <=>  no included candidate for row (reference invalid row)
__global__ void kcombine(const float* __restrict__ pV, const int* __restrict__ pI,
                         int* __restrict__ nidx, int nc) {
    int s = blockIdx.x * 256 + threadIdx.x;
    if (s >= NROWS * NS) return;
    float bv = INFINITY;
    int bi = 0x7FFFFFFF;
    for (int c = 0; c < nc; ++c) {
        float v = pV[(size_t)s * nc + c];
        int idx = pI[(size_t)s * nc + c];
        if (v < bv || (v == bv && idx < bi)) { bv = v; bi = idx; }
    }
    nidx[s] = (bv == INFINITY) ? -1 : bi;
}

// ---------------- fallback (small ws): fused sample, min-key partials -----
__global__ __launch_bounds__(256, 2) void ksample(
        const __bf16* __restrict__ xb, const float* __restrict__ sqv,
        float* __restrict__ pV, int* __restrict__ pI) {
    const int lane  = threadIdx.x & 63;
    const int chunk = (blockIdx.x << 2) + (threadIdx.x >> 6);
    const int grp   = blockIdx.y;
    const int rlo = lane & 15;
    const int khi = lane >> 4;

    const int afr = grp * 8 + (rlo >> 1) + ((rlo & 1) << 11);
    v8bf ah[4];
#pragma unroll
    for (int ks = 0; ks < 4; ++ks)
        ah[ks] = *(const v8bf*)(xb + (size_t)afr * DIM + ks * 32 + khi * 8);
    const int base = grp * 8 + khi * 2;
    float sqA[4];
    sqA[0] = sqv[base];
    sqA[1] = sqv[base + 2048];
    sqA[2] = sqv[base + 1];
    sqA[3] = sqv[base + 2049];
    const uint32_t P0 = (uint32_t)base;
    const uint32_t P1 = (uint32_t)(base + 1);

    float    bestV[4][NS];
    uint32_t bestP[4];
#pragma unroll
    for (int q = 0; q < 4; ++q) {
        bestP[q] = 0u;
#pragma unroll
        for (int j = 0; j < NS; ++j) bestV[q][j] = INFINITY;
    }
    const int tcol0 = chunk * 256 + rlo;

    v8bf bhn[4];
    float sqn;
    {
        const size_t boff = (size_t)tcol0 * DIM + khi * 8;
#pragma unroll
        for (int ks = 0; ks < 4; ++ks) bhn[ks] = *(const v8bf*)(xb + boff + ks * 32);
        sqn = sqv[tcol0];
    }

#pragma unroll 1
    for (int cg = 0; cg < 16; ++cg) {
        v8bf bhc[4];
#pragma unroll
        for (int ks = 0; ks < 4; ++ks) bhc[ks] = bhn[ks];
        const float sqB = sqn;
        const int tcol = tcol0 + cg * 16;
        if (cg < 15) {
            const size_t boff = (size_t)(tcol + 16) * DIM + khi * 8;
#pragma unroll
            for (int ks = 0; ks < 4; ++ks) bhn[ks] = *(const v8bf*)(xb + boff + ks * 32);
            sqn = sqv[tcol + 16];
        }
        v4f acc = {0.f, 0.f, 0.f, 0.f};
#pragma unroll
        for (int ks = 0; ks < 4; ++ks)
            acc = __builtin_amdgcn_mfma_f32_16x16x32_bf16(ah[ks], bhc[ks], acc, 0, 0, 0);
        const int tBlk = tcol >> 3;
        const bool bd0 = (tBlk != grp);
        const bool bd1 = (tBlk != grp + 256);
        float nw[4];
#pragma unroll
        for (int q = 0; q < 4; ++q) {
            float d2  = fmaf(-2.0f, acc[q], sqA[q] + sqB);
            float l1  = __log2f(d2);
            float t2  = fmaf(-0.25f, d2, 1.0f);
            float l2  = __log2f(t2);
            float wiv = exp2f(fmaf(63.0f, l1, 62.5f * l2));
            bool incl = (d2 < 1.96f) && ((q & 1) ? bd1 : bd0);
            nw[q] = incl ? -wiv : -INFINITY;
        }
        const uint32_t tB = (uint32_t)tcol;
#pragma unroll
        for (int j = 0; j < NS; ++j) {
            uint32_t L0 = ((P0 * 7u + (uint32_t)j) << 12) + tB;
            uint32_t L1 = ((P1 * 7u + (uint32_t)j) << 12) + tB;
            uint32_t o0, o1, o2, o3;
            threefry2x32(L0, L0 + HALF_CNT, o0, o1);
            threefry2x32(L1, L1 + HALF_CNT, o2, o3);
            float vv[4];
            vv[0] = __log2f(__uint_as_float((o0 >> 9) | 0x3f800000u) - 1.0f + 1.17549435e-38f) * nw[0];
            vv[1] = __log2f(__uint_as_float((o1 >> 9) | 0x3f800000u) - 1.0f + 1.17549435e-38f) * nw[1];
            vv[2] = __log2f(__uint_as_float((o2 >> 9) | 0x3f800000u) - 1.0f + 1.17549435e-38f) * nw[2];
            vv[3] = __log2f(__uint_as_float((o3 >> 9) | 0x3f800000u) - 1.0f + 1.17549435e-38f) * nw[3];
            const uint32_t keep = ~(0xFu << (4 * j));
            const uint32_t put  = ((uint32_t)cg) << (4 * j);
#pragma unroll
            for (int q = 0; q < 4; ++q) {
                bool lt = vv[q] < bestV[q][j];
                uint32_t np = (bestP[q] & keep) | put;
                bestV[q][j] = lt ? vv[q] : bestV[q][j];
                bestP[q]    = lt ? np : bestP[q];
            }
        }
    }
#pragma unroll
    for (int q = 0; q < 4; ++q) {
        const int a = base + (q >> 1) + ((q & 1) << 11);
#pragma unroll
        for (int j = 0; j < NS; ++j) {
            float v = bestV[q][j];
            int idx = tcol0 + (int)((bestP[q] >> (4 * j)) & 0xFu) * 16;
#pragma unroll
            for (int m = 1; m < 16; m <<= 1) {
                float v2 = __shfl_xor(v, m, 16);
                int   i2 = __shfl_xor(idx, m, 16);
                if (v2 < v || (v2 == v && i2 < idx)) { v = v2; idx = i2; }
            }
            if (rlo == 0) {
                size_t s = ((size_t)a * NS + j) * TCH + chunk;
                pV[s] = v;
                pI[s] = idx;
            }
        }
    }
}

// ---------------- kernel 4: uniform fallback for invalid rows -------------
__global__ void kfixup(int* __restrict__ nidx) {
    const int i = blockIdx.x;
    if (nidx[(size_t)i * NS] >= 0) return;   // normal case: immediate exit
    const int lane = threadIdx.x;            // 64
    for (int j = 0; j < NS; ++j) {
        float bv = -INFINITY;
        int bi = 0x7FFFFFFF;
        for (int t = lane; t < NROWS; t += 64) {
            uint32_t o0, o1;
            float g;
            if (i < 2048) {
                uint32_t L = (((uint32_t)(i * NS + j)) << 12) + (uint32_t)t;
                threefry2x32(L, L + HALF_CNT, o0, o1);
                g = gumbel_of(o0);
            } else {
                uint32_t L = (((uint32_t)((i - 2048) * NS + j)) << 12) + (uint32_t)t;
                threefry2x32(L, L + HALF_CNT, o0, o1);
                g = gumbel_of(o1);
            }
            if (g > bv) { bv = g; bi = t; }
        }
#pragma unroll
        for (int m = 1; m < 64; m <<= 1) {
            float v2 = __shfl_xor(bv, m, 64);
            int   i2 = __shfl_xor(bi, m, 64);
            if (v2 > bv || (v2 == bv && i2 < bi)) { bv = v2; bi = i2; }
        }
        if (lane == 0) nidx[i * NS + j] = bi;
    }
}

// ---------------- kernel 5: triplet losses --------------------------------
__global__ void kloss(const float* __restrict__ x, const int* __restrict__ nidx,
                      float* __restrict__ loss) {
    int s = blockIdx.x * 256 + threadIdx.x;
    if (s >= NROWS * NS) return;
    int i = s / NS, j = s - i * NS;
    int r = i & (KB - 1), blk = i >> 3;
    int po = (j < r) ? j : j + 1;
    int p = blk * KB + po;
    int n = nidx[s] & (NROWS - 1);      // defensive clamp (no-op when correct)
    const float4* A  = (const float4*)(x + (size_t)i * DIM);
    const float4* P  = (const float4*)(x + (size_t)p * DIM);
    const float4* Ng = (const float4*)(x + (size_t)n * DIM);
    float sap = 0.0f, san = 0.0f;
#pragma unroll 8
    for (int k = 0; k < DIM / 4; ++k) {
        float4 a = A[k], pv = P[k], nv = Ng[k];
        float d;
        d = a.x - pv.x + 1e-6f; sap += d * d;
        d = a.y - pv.y + 1e-6f; sap += d * d;
        d = a.z - pv.z + 1e-6f; sap += d * d;
        d = a.w - pv.w + 1e-6f; sap += d * d;
        d = a.x - nv.x + 1e-6f; san += d * d;
        d = a.y - nv.y + 1e-6f; san += d * d;
        d = a.z - nv.z + 1e-6f; san += d * d;
        d = a.w - nv.w + 1e-6f; san += d * d;
    }
    loss[s] = fmaxf(sqrtf(sap) - sqrtf(san) + 1.0f, 0.0f);
}

// ---------------- kernel 6: mean ------------------------------------------
__global__ void kreduce(const float* __restrict__ loss, float* __restrict__ out) {
    __shared__ float part[4];
    const int tid = threadIdx.x;
    float sum = 0.0f;
    for (int s = tid; s < NROWS * NS; s += 256) sum += loss[s];
#pragma unroll
    for (int m = 32; m > 0; m >>= 1) sum += __shfl_xor(sum, m, 64);
    if ((tid & 63) == 0) part[tid >> 6] = sum;
    __syncthreads();
    if (tid == 0) out[0] = (part[0] + part[1] + part[2] + part[3]) / 28672.0f;
}

extern "C" void kernel_launch(void* const* d_in, const int* in_sizes, int n_in,
                              void* d_out, int out_size, void* d_ws, size_t ws_size,
                              hipStream_t stream) {
    const float* x = (const float*)d_in[0];
    float* out = (float*)d_out;

    uint8_t* w = (uint8_t*)d_ws;
    size_t off = 0;
    auto take = [&](size_t bytes) {
        void* p = w + off;
        off = (off + bytes + 255) & ~(size_t)255;
        return p;
    };
    __bf16* xb   = (__bf16*)take((size_t)NROWS * DIM * 2);
    float*  sqv  = (float*)take((size_t)NROWS * 4);
    int*    nidx = (int*)take((size_t)NROWS * NS * 4);
    float*  loss = (float*)take((size_t)NROWS * NS * 4);
    int*    cnt  = (int*)take((size_t)NPAIR * 16 * 4);   // per-(pair,chunk)
    const size_t prefix = off;
    const size_t t16_b = (size_t)NPAIR * 16 * 256 * 2;   // 16.8 MB
    const size_t nwp_b = (size_t)NPAIR * 16 * 256 * 8;   // 67.1 MB
    const size_t pv4_b = (size_t)NROWS * NS * NSEG * 4;  // 0.46 MB
    const size_t NEED_BIG = prefix + ((t16_b + 255) & ~(size_t)255)
                          + ((nwp_b + 255) & ~(size_t)255)
                          + 2 * ((pv4_b + 255) & ~(size_t)255);

    knorm<<<NROWS, 64, 0, stream>>>(x, xb, sqv);

    if (ws_size >= NEED_BIG) {
        unsigned short* t16 = (unsigned short*)take(t16_b);
        float2*         nwp = (float2*)take(nwp_b);
        float*          pV  = (float*)take(pv4_b);
        int*            pI  = (int*)take(pv4_b);
        kdist<<<dim3(TCH / 4, 256), 256, 0, stream>>>(xb, sqv, cnt, t16, nwp);
        kgum<<<NPAIR * 16 / 4, 256, 0, stream>>>(cnt, t16, nwp, pV, pI);
        kcombine<<<(NROWS * NS + 255) / 256, 256, 0, stream>>>(pV, pI, nidx, NSEG);
    } else {
        float* pV = (float*)take((size_t)NROWS * NS * TCH * 4);
        int*   pI = (int*)take((size_t)NROWS * NS * TCH * 4);
        ksample<<<dim3(TCH / 4, 256), 256, 0, stream>>>(xb, sqv, pV, pI);
        kcombine<<<(NROWS * NS + 255) / 256, 256, 0, stream>>>(pV, pI, nidx, TCH);
    }

    kfixup<<<NROWS, 64, 0, stream>>>(nidx);
    kloss<<<(NROWS * NS + 255) / 256, 256, 0, stream>>>(x, nidx, loss);
    kreduce<<<1, 256, 0, stream>>>(loss, out);
}

// Round 11
// 200.097 us; speedup vs baseline: 1.3011x; 1.0095x over previous
//
#include <hip/hip_runtime.h>
#include <stdint.h>

#define NROWS 4096
#define DIM   128
#define KB    8
#define NS    7            // K-1 negatives per anchor
#define TCH   16           // candidate chunks (256 cands each)
#define NSEG  4            // partial-combine groups (4 chunks each)
#define NPAIR 2048
#define HALF_CNT 58720256u // (4096*7*4096)/2

typedef __bf16 v8bf __attribute__((ext_vector_type(8)));
typedef float  v4f  __attribute__((ext_vector_type(4)));

__device__ __forceinline__ uint32_t rotl32(uint32_t x, int r) {
    return (x << r) | (x >> (32 - r));
}

// JAX threefry2x32, key = [0, 42], 20 rounds. (c0,c1)=(L, L+HALF_CNT):
// o0 = bits for flat index L, o1 = bits for flat index L+HALF_CNT.
__device__ __forceinline__ void threefry2x32(uint32_t c0, uint32_t c1,
                                             uint32_t& o0, uint32_t& o1) {
    const uint32_t ks0 = 0u;
    const uint32_t ks1 = 42u;
    const uint32_t ks2 = 0x1BD11BDAu ^ ks0 ^ ks1;
    uint32_t x0 = c0 + ks0;
    uint32_t x1 = c1 + ks1;
#define TF_R(r) { x0 += x1; x1 = rotl32(x1, r); x1 ^= x0; }
    TF_R(13) TF_R(15) TF_R(26) TF_R(6)
    x0 += ks1; x1 += ks2 + 1u;
    TF_R(17) TF_R(29) TF_R(16) TF_R(24)
    x0 += ks2; x1 += ks0 + 2u;
    TF_R(13) TF_R(15) TF_R(26) TF_R(6)
    x0 += ks0; x1 += ks1 + 3u;
    TF_R(17) TF_R(29) TF_R(16) TF_R(24)
    x0 += ks1; x1 += ks2 + 4u;
    TF_R(13) TF_R(15) TF_R(26) TF_R(6)
    x0 += ks2; x1 += ks0 + 5u;
#undef TF_R
    o0 = x0; o1 = x1;
}

// gumbel = -ln(-ln(u)) (used only by the never-fires kfixup + fallback)
__device__ __forceinline__ float gumbel_of(uint32_t b) {
    float f = __uint_as_float((b >> 9) | 0x3f800000u) - 1.0f;   // [0,1)
    float u = f + 1.17549435e-38f;
    float l1 = __log2f(u);
    float inner = -0.69314718055994531f * l1;
    float l2 = __log2f(inner);
    return -0.69314718055994531f * l2;
}

// ---------------- kernel 1: normalize -> bf16 plane + sq ------------------
__global__ void knorm(const float* __restrict__ x, __bf16* __restrict__ xb,
                      float* __restrict__ sqv) {
    const int i = blockIdx.x;
    const int t = threadIdx.x;  // 64 threads, 2 elems each
    float2 v = ((const float2*)(x + (size_t)i * DIM))[t];
    float s = v.x * v.x + v.y * v.y;
#pragma unroll
    for (int m = 32; m > 0; m >>= 1) s += __shfl_xor(s, m, 64);
    float norm = sqrtf(s) + 1e-5f;
    float ox = v.x / norm, oy = v.y / norm;
    union { __bf16 b[2]; uint32_t u; } ph;
    ph.b[0] = (__bf16)ox; ph.b[1] = (__bf16)oy;
    ((uint32_t*)xb)[i * 64 + t] = ph.u;
    float s2 = ox * ox + oy * oy;
#pragma unroll
    for (int m = 32; m > 0; m >>= 1) s2 += __shfl_xor(s2, m, 64);
    if (t == 0) sqv[i] = s2;
}

// ---------------- kernel 2a: MFMA dists -> compacted lists (negwinv) ------
// Per (pair,chunk) 256-slot region owned by one 16-lane group: register
// running count, contiguous appends, no atomics. Stores negwinv = -1/w so
// kgum can use the argmin E/w formulation (one log per sample-chain).
__global__ __launch_bounds__(256, 4) void kdist(
        const __bf16* __restrict__ xb, const float* __restrict__ sqv,
        int* __restrict__ cnt, unsigned short* __restrict__ t16,
        float2* __restrict__ nwp) {
    const int lane  = threadIdx.x & 63;
    const int chunk = (blockIdx.x << 2) + (threadIdx.x >> 6);   // 0..15
    const int grp   = blockIdx.y;   // 0..255
    const int rlo = lane & 15;
    const int khi = lane >> 4;
    const unsigned int below = (1u << rlo) - 1u;

    const int afr = grp * 8 + (rlo >> 1) + ((rlo & 1) << 11);
    v8bf ah[4];
#pragma unroll
    for (int ks = 0; ks < 4; ++ks)
        ah[ks] = *(const v8bf*)(xb + (size_t)afr * DIM + ks * 32 + khi * 8);

    const int base = grp * 8 + khi * 2;   // pairA = base, pairB = base+1
    float sqA[4];
    sqA[0] = sqv[base];
    sqA[1] = sqv[base + 2048];
    sqA[2] = sqv[base + 1];
    sqA[3] = sqv[base + 2049];

    const int rbA = ((base)     * 16 + chunk) << 8;
    const int rbB = ((base + 1) * 16 + chunk) << 8;
    unsigned int cA = 0, cB = 0;          // uniform within 16-group

    const int tcol0 = chunk * 256 + rlo;

    v8bf bhn[4];
    float sqn;
    {
        const size_t boff = (size_t)tcol0 * DIM + khi * 8;
#pragma unroll
        for (int ks = 0; ks < 4; ++ks) bhn[ks] = *(const v8bf*)(xb + boff + ks * 32);
        sqn = sqv[tcol0];
    }

#pragma unroll 1
    for (int cg = 0; cg < 16; ++cg) {
        v8bf bhc[4];
#pragma unroll
        for (int ks = 0; ks < 4; ++ks) bhc[ks] = bhn[ks];
        const float sqB = sqn;
        const int tcol = tcol0 + cg * 16;

        if (cg < 15) {
            const size_t boff = (size_t)(tcol + 16) * DIM + khi * 8;
#pragma unroll
            for (int ks = 0; ks < 4; ++ks) bhn[ks] = *(const v8bf*)(xb + boff + ks * 32);
            sqn = sqv[tcol + 16];
        }

        v4f acc = {0.f, 0.f, 0.f, 0.f};
#pragma unroll
        for (int ks = 0; ks < 4; ++ks)
            acc = __builtin_amdgcn_mfma_f32_16x16x32_bf16(ah[ks], bhc[ks], acc, 0, 0, 0);

        const int tBlk = tcol >> 3;
        const bool bd0 = (tBlk != grp);
        const bool bd1 = (tBlk != grp + 256);

        float nw[4];
        bool  ic[4];
#pragma unroll
        for (int q = 0; q < 4; ++q) {
            float d2  = fmaf(-2.0f, acc[q], sqA[q] + sqB);
            float l1  = __log2f(d2);
            float t2  = fmaf(-0.25f, d2, 1.0f);
            float l2  = __log2f(t2);
            // negwinv = -exp(lg)^-1 : lg_nat = -63 ln(d2) - 62.5 ln(1-d2/4)
            float wiv = exp2f(fmaf(63.0f, l1, 62.5f * l2));
            bool incl = (d2 < 1.96f) && ((q & 1) ? bd1 : bd0);
            ic[q] = incl;
            nw[q] = incl ? -wiv : -INFINITY;
        }

        const bool uA = ic[0] | ic[1];
        const bool uB = ic[2] | ic[3];
        unsigned long long ballA = __ballot(uA);
        unsigned long long ballB = __ballot(uB);
        unsigned int subA = (unsigned int)((ballA >> (khi * 16)) & 0xFFFFull);
        unsigned int subB = (unsigned int)((ballB >> (khi * 16)) & 0xFFFFull);
        if (uA) {
            int slot = rbA + (int)cA + __popc(subA & below);
            t16[slot] = (unsigned short)tcol;
            nwp[slot] = make_float2(nw[0], nw[1]);
        }
        if (uB) {
            int slot = rbB + (int)cB + __popc(subB & below);
            t16[slot] = (unsigned short)tcol;
            nwp[slot] = make_float2(nw[2], nw[3]);
        }
        cA += (unsigned int)__popc(subA);
        cB += (unsigned int)__popc(subB);
    }

    if (rlo == 0) {
        cnt[base * 16 + chunk]       = (int)cA;
        cnt[(base + 1) * 16 + chunk] = (int)cB;
    }
}

// ---------------- kernel 2b: argmin E/w, LDS-staged region scan -----------
// grid = 8192 blocks x 256: block = 4 consecutive regions (same pair p).
// Each wave stages its region's list (<=256 x 10B) into LDS with bulk
// coalesced loads (deep-pipelined; hides L3/HBM latency), then runs the
// chain loop from LDS (latency ~120cyc, hidden under the ~200cyc threefry).
// Lane = (entry-octet eo, sample j). Tie-break total order (key smaller)||
// (equal && t smaller) keeps the result order-independent.
__global__ __launch_bounds__(256, 8) void kgum(
        const int* __restrict__ cnt, const unsigned short* __restrict__ t16,
        const float2* __restrict__ nwp,
        float* __restrict__ pV, int* __restrict__ pI) {
    const int wid  = threadIdx.x >> 6;            // 0..3
    const int rid  = (blockIdx.x << 2) + wid;     // region id 0..32767
    const int p    = rid >> 4;                    // pair
    const int lane = threadIdx.x & 63;
    const int j    = lane & 7;
    const int eo   = lane >> 3;                   // entry-octet slot 0..7
    const bool jv  = (j < 7);
    const uint32_t pb = ((uint32_t)p * 7u + (uint32_t)j) << 12;

    __shared__ unsigned short st[4][256];
    __shared__ float2         snw[4][256];

    const int n  = cnt[rid];
    const int rb = rid << 8;

    // bulk stage to LDS: 64-lane coalesced, up to 4 independent loads/wave
    for (int s = lane; s < n; s += 64) {
        st[wid][s]  = t16[rb + s];
        snw[wid][s] = nwp[rb + s];
    }
    __syncthreads();

    float bkA = INFINITY, bkB = INFINITY;
    int   btA = 0x7FFFFFFF, btB = 0x7FFFFFFF;

#pragma unroll 1
    for (int e = eo; e < n; e += 8) {
        const uint32_t t = st[wid][e];
        const float2 nw  = snw[wid][e];
        const uint32_t L = pb + t;
        uint32_t o0, o1;
        threefry2x32(L, L + HALF_CNT, o0, o1);
        float fA = __uint_as_float((o0 >> 9) | 0x3f800000u) - 1.0f;
        float fB = __uint_as_float((o1 >> 9) | 0x3f800000u) - 1.0f;
        float l1A = __log2f(fA + 1.17549435e-38f);
        float l1B = __log2f(fB + 1.17549435e-38f);
        float kA = jv ? l1A * nw.x : INFINITY;
        float kB = jv ? l1B * nw.y : INFINITY;
        const int ti = (int)t;
        if (kA < bkA || (kA == bkA && ti < btA)) { bkA = kA; btA = ti; }
        if (kB < bkB || (kB == bkB && ti < btB)) { bkB = kB; btB = ti; }
    }

    // reduce across entry-octet slots (xor masks 8,16,32): min-key
#pragma unroll
    for (int m = 8; m < 64; m <<= 1) {
        float v2 = __shfl_xor(bkA, m, 64);
        int   t2 = __shfl_xor(btA, m, 64);
        if (v2 < bkA || (v2 == bkA && t2 < btA)) { bkA = v2; btA = t2; }
        v2 = __shfl_xor(bkB, m, 64);
        t2 = __shfl_xor(btB, m, 64);
        if (v2 < bkB || (v2 == bkB && t2 < btB)) { bkB = v2; btB = t2; }
    }

    // block-level reduction over the 4 same-pair regions -> one partial
    __shared__ float sV[4][2][NS];
    __shared__ int   sT[4][2][NS];
    if (lane < NS) {
        sV[wid][0][lane] = bkA; sT[wid][0][lane] = btA;
        sV[wid][1][lane] = bkB; sT[wid][1][lane] = btB;
    }
    __syncthreads();
    if (threadIdx.x < 2 * NS) {
        const int r = threadIdx.x / NS, jj = threadIdx.x - r * NS;
        float v = sV[0][r][jj];
        int   t = sT[0][r][jj];
#pragma unroll
        for (int w = 1; w < 4; ++w) {
            float v2 = sV[w][r][jj];
            int   t2 = sT[w][r][jj];
            if (v2 < v || (v2 == v && t2 < t)) { v = v2; t = t2; }
        }
        const int cgrp = blockIdx.x & 3;
        size_t s = ((size_t)(p + r * 2048) * NS + jj) * NSEG + cgrp;
        pV[s] = v; pI[s] = t;
    }
}

// ---------------- kernel 3: combine partials (min-key) -> n_idx -----------
// key == +inf  <=>  no included candidate for row (reference invalid row)
__global__ void kcombine(const float* __restrict__ pV, const int* __restrict__ pI,
                         int* __restrict__ nidx, int nc) {
    int s = blockIdx.x * 256 + threadIdx.x;
    if (s >= NROWS * NS) return;
    float bv = INFINITY;
    int bi = 0x7FFFFFFF;
    for (int c = 0; c < nc; ++c) {
        float v = pV[(size_t)s * nc + c];
        int idx = pI[(size_t)s * nc + c];
        if (v < bv || (v == bv && idx < bi)) { bv = v; bi = idx; }
    }
    nidx[s] = (bv == INFINITY) ? -1 : bi;
}

// ---------------- fallback (small ws): fused sample, min-key partials -----
__global__ __launch_bounds__(256, 2) void ksample(
        const __bf16* __restrict__ xb, const float* __restrict__ sqv,
        float* __restrict__ pV, int* __restrict__ pI) {
    const int lane  = threadIdx.x & 63;
    const int chunk = (blockIdx.x << 2) + (threadIdx.x >> 6);
    const int grp   = blockIdx.y;
    const int rlo = lane & 15;
    const int khi = lane >> 4;

    const int afr = grp * 8 + (rlo >> 1) + ((rlo & 1) << 11);
    v8bf ah[4];
#pragma unroll
    for (int ks = 0; ks < 4; ++ks)
        ah[ks] = *(const v8bf*)(xb + (size_t)afr * DIM + ks * 32 + khi * 8);
    const int base = grp * 8 + khi * 2;
    float sqA[4];
    sqA[0] = sqv[base];
    sqA[1] = sqv[base + 2048];
    sqA[2] = sqv[base + 1];
    sqA[3] = sqv[base + 2049];
    const uint32_t P0 = (uint32_t)base;
    const uint32_t P1 = (uint32_t)(base + 1);

    float    bestV[4][NS];
    uint32_t bestP[4];
#pragma unroll
    for (int q = 0; q < 4; ++q) {
        bestP[q] = 0u;
#pragma unroll
        for (int j = 0; j < NS; ++j) bestV[q][j] = INFINITY;
    }
    const int tcol0 = chunk * 256 + rlo;

    v8bf bhn[4];
    float sqn;
    {
        const size_t boff = (size_t)tcol0 * DIM + khi * 8;
#pragma unroll
        for (int ks = 0; ks < 4; ++ks) bhn[ks] = *(const v8bf*)(xb + boff + ks * 32);
        sqn = sqv[tcol0];
    }

#pragma unroll 1
    for (int cg = 0; cg < 16; ++cg) {
        v8bf bhc[4];
#pragma unroll
        for (int ks = 0; ks < 4; ++ks) bhc[ks] = bhn[ks];
        const float sqB = sqn;
        const int tcol = tcol0 + cg * 16;
        if (cg < 15) {
            const size_t boff = (size_t)(tcol + 16) * DIM + khi * 8;
#pragma unroll
            for (int ks = 0; ks < 4; ++ks) bhn[ks] = *(const v8bf*)(xb + boff + ks * 32);
            sqn = sqv[tcol + 16];
        }
        v4f acc = {0.f, 0.f, 0.f, 0.f};
#pragma unroll
        for (int ks = 0; ks < 4; ++ks)
            acc = __builtin_amdgcn_mfma_f32_16x16x32_bf16(ah[ks], bhc[ks], acc, 0, 0, 0);
        const int tBlk = tcol >> 3;
        const bool bd0 = (tBlk != grp);
        const bool bd1 = (tBlk != grp + 256);
        float nw[4];
#pragma unroll
        for (int q = 0; q < 4; ++q) {
            float d2  = fmaf(-2.0f, acc[q], sqA[q] + sqB);
            float l1  = __log2f(d2);
            float t2  = fmaf(-0.25f, d2, 1.0f);
            float l2  = __log2f(t2);
            float wiv = exp2f(fmaf(63.0f, l1, 62.5f * l2));
            bool incl = (d2 < 1.96f) && ((q & 1) ? bd1 : bd0);
            nw[q] = incl ? -wiv : -INFINITY;
        }
        const uint32_t tB = (uint32_t)tcol;
#pragma unroll
        for (int j = 0; j < NS; ++j) {
            uint32_t L0 = ((P0 * 7u + (uint32_t)j) << 12) + tB;
            uint32_t L1 = ((P1 * 7u + (uint32_t)j) << 12) + tB;
            uint32_t o0, o1, o2, o3;
            threefry2x32(L0, L0 + HALF_CNT, o0, o1);
            threefry2x32(L1, L1 + HALF_CNT, o2, o3);
            float vv[4];
            vv[0] = __log2f(__uint_as_float((o0 >> 9) | 0x3f800000u) - 1.0f + 1.17549435e-38f) * nw[0];
            vv[1] = __log2f(__uint_as_float((o1 >> 9) | 0x3f800000u) - 1.0f + 1.17549435e-38f) * nw[1];
            vv[2] = __log2f(__uint_as_float((o2 >> 9) | 0x3f800000u) - 1.0f + 1.17549435e-38f) * nw[2];
            vv[3] = __log2f(__uint_as_float((o3 >> 9) | 0x3f800000u) - 1.0f + 1.17549435e-38f) * nw[3];
            const uint32_t keep = ~(0xFu << (4 * j));
            const uint32_t put  = ((uint32_t)cg) << (4 * j);
#pragma unroll
            for (int q = 0; q < 4; ++q) {
                bool lt = vv[q] < bestV[q][j];
                uint32_t np = (bestP[q] & keep) | put;
                bestV[q][j] = lt ? vv[q] : bestV[q][j];
                bestP[q]    = lt ? np : bestP[q];
            }
        }
    }
#pragma unroll
    for (int q = 0; q < 4; ++q) {
        const int a = base + (q >> 1) + ((q & 1) << 11);
#pragma unroll
        for (int j = 0; j < NS; ++j) {
            float v = bestV[q][j];
            int idx = tcol0 + (int)((bestP[q] >> (4 * j)) & 0xFu) * 16;
#pragma unroll
            for (int m = 1; m < 16; m <<= 1) {
                float v2 = __shfl_xor(v, m, 16);
                int   i2 = __shfl_xor(idx, m, 16);
                if (v2 < v || (v2 == v && i2 < idx)) { v = v2; idx = i2; }
            }
            if (rlo == 0) {
                size_t s = ((size_t)a * NS + j) * TCH + chunk;
                pV[s] = v;
                pI[s] = idx;
            }
        }
    }
}

// ---------------- kernel 4: uniform fallback for invalid rows -------------
__global__ void kfixup(int* __restrict__ nidx) {
    const int i = blockIdx.x;
    if (nidx[(size_t)i * NS] >= 0) return;   // normal case: immediate exit
    const int lane = threadIdx.x;            // 64
    for (int j = 0; j < NS; ++j) {
        float bv = -INFINITY;
        int bi = 0x7FFFFFFF;
        for (int t = lane; t < NROWS; t += 64) {
            uint32_t o0, o1;
            float g;
            if (i < 2048) {
                uint32_t L = (((uint32_t)(i * NS + j)) << 12) + (uint32_t)t;
                threefry2x32(L, L + HALF_CNT, o0, o1);
                g = gumbel_of(o0);
            } else {
                uint32_t L = (((uint32_t)((i - 2048) * NS + j)) << 12) + (uint32_t)t;
                threefry2x32(L, L + HALF_CNT, o0, o1);
                g = gumbel_of(o1);
            }
            if (g > bv) { bv = g; bi = t; }
        }
#pragma unroll
        for (int m = 1; m < 64; m <<= 1) {
            float v2 = __shfl_xor(bv, m, 64);
            int   i2 = __shfl_xor(bi, m, 64);
            if (v2 > bv || (v2 == bv && i2 < bi)) { bv = v2; bi = i2; }
        }
        if (lane == 0) nidx[i * NS + j] = bi;
    }
}

// ---------------- kernel 5: triplet losses --------------------------------
__global__ void kloss(const float* __restrict__ x, const int* __restrict__ nidx,
                      float* __restrict__ loss) {
    int s = blockIdx.x * 256 + threadIdx.x;
    if (s >= NROWS * NS) return;
    int i = s / NS, j = s - i * NS;
    int r = i & (KB - 1), blk = i >> 3;
    int po = (j < r) ? j : j + 1;
    int p = blk * KB + po;
    int n = nidx[s] & (NROWS - 1);      // defensive clamp (no-op when correct)
    const float4* A  = (const float4*)(x + (size_t)i * DIM);
    const float4* P  = (const float4*)(x + (size_t)p * DIM);
    const float4* Ng = (const float4*)(x + (size_t)n * DIM);
    float sap = 0.0f, san = 0.0f;
#pragma unroll 8
    for (int k = 0; k < DIM / 4; ++k) {
        float4 a = A[k], pv = P[k], nv = Ng[k];
        float d;
        d = a.x - pv.x + 1e-6f; sap += d * d;
        d = a.y - pv.y + 1e-6f; sap += d * d;
        d = a.z - pv.z + 1e-6f; sap += d * d;
        d = a.w - pv.w + 1e-6f; sap += d * d;
        d = a.x - nv.x + 1e-6f; san += d * d;
        d = a.y - nv.y + 1e-6f; san += d * d;
        d = a.z - nv.z + 1e-6f; san += d * d;
        d = a.w - nv.w + 1e-6f; san += d * d;
    }
    loss[s] = fmaxf(sqrtf(sap) - sqrtf(san) + 1.0f, 0.0f);
}

// ---------------- kernel 6: mean ------------------------------------------
__global__ void kreduce(const float* __restrict__ loss, float* __restrict__ out) {
    __shared__ float part[4];
    const int tid = threadIdx.x;
    float sum = 0.0f;
    for (int s = tid; s < NROWS * NS; s += 256) sum += loss[s];
#pragma unroll
    for (int m = 32; m > 0; m >>= 1) sum += __shfl_xor(sum, m, 64);
    if ((tid & 63) == 0) part[tid >> 6] = sum;
    __syncthreads();
    if (tid == 0) out[0] = (part[0] + part[1] + part[2] + part[3]) / 28672.0f;
}

extern "C" void kernel_launch(void* const* d_in, const int* in_sizes, int n_in,
                              void* d_out, int out_size, void* d_ws, size_t ws_size,
                              hipStream_t stream) {
    const float* x = (const float*)d_in[0];
    float* out = (float*)d_out;

    uint8_t* w = (uint8_t*)d_ws;
    size_t off = 0;
    auto take = [&](size_t bytes) {
        void* p = w + off;
        off = (off + bytes + 255) & ~(size_t)255;
        return p;
    };
    __bf16* xb   = (__bf16*)take((size_t)NROWS * DIM * 2);
    float*  sqv  = (float*)take((size_t)NROWS * 4);
    int*    nidx = (int*)take((size_t)NROWS * NS * 4);
    float*  loss = (float*)take((size_t)NROWS * NS * 4);
    int*    cnt  = (int*)take((size_t)NPAIR * 16 * 4);   // per-(pair,chunk)
    const size_t prefix = off;
    const size_t t16_b = (size_t)NPAIR * 16 * 256 * 2;   // 16.8 MB
    const size_t nwp_b = (size_t)NPAIR * 16 * 256 * 8;   // 67.1 MB
    const size_t pv4_b = (size_t)NROWS * NS * NSEG * 4;  // 0.46 MB
    const size_t NEED_BIG = prefix + ((t16_b + 255) & ~(size_t)255)
                          + ((nwp_b + 255) & ~(size_t)255)
                          + 2 * ((pv4_b + 255) & ~(size_t)255);

    knorm<<<NROWS, 64, 0, stream>>>(x, xb, sqv);

    if (ws_size >= NEED_BIG) {
        unsigned short* t16 = (unsigned short*)take(t16_b);
        float2*         nwp = (float2*)take(nwp_b);
        float*          pV  = (float*)take(pv4_b);
        int*            pI  = (int*)take(pv4_b);
        kdist<<<dim3(TCH / 4, 256), 256, 0, stream>>>(xb, sqv, cnt, t16, nwp);
        kgum<<<NPAIR * 16 / 4, 256, 0, stream>>>(cnt, t16, nwp, pV, pI);
        kcombine<<<(NROWS * NS + 255) / 256, 256, 0, stream>>>(pV, pI, nidx, NSEG);
    } else {
        float* pV = (float*)take((size_t)NROWS * NS * TCH * 4);
        int*   pI = (int*)take((size_t)NROWS * NS * TCH * 4);
        ksample<<<dim3(TCH / 4, 256), 256, 0, stream>>>(xb, sqv, pV, pI);
        kcombine<<<(NROWS * NS + 255) / 256, 256, 0, stream>>>(pV, pI, nidx, TCH);
    }

    kfixup<<<NROWS, 64, 0, stream>>>(nidx);
    kloss<<<(NROWS * NS + 255) / 256, 256, 0, stream>>>(x, nidx, loss);
    kreduce<<<1, 256, 0, stream>>>(loss, out);
}